// Round 1
// baseline (725.537 us; speedup 1.0000x reference)
//
#include <hip/hip_runtime.h>

#define NN 50000
#define NE 800000
#define NB 512
#define DIN 128
#define DD2 200
#define C1 100
#define C2 20
#define DHH 64
#define HH1 128
#define HH2 32

// ---------------- CSR build ----------------
__global__ void k_count(const int* __restrict__ dst, int* __restrict__ cnt) {
    int e = blockIdx.x * 256 + threadIdx.x;
    if (e < NE) atomicAdd(&cnt[dst[e]], 1);
}

__global__ void k_gcount(const int* __restrict__ gid, int* __restrict__ gcnt) {
    int n = blockIdx.x * 256 + threadIdx.x;
    if (n < NN) atomicAdd(&gcnt[gid[n]], 1);
}

__global__ void k_scan(const int* __restrict__ cnt, int* __restrict__ row_ptr,
                       int* __restrict__ cursor, int n) {
    __shared__ int wsum[16];
    __shared__ int s_base;
    const int tid = threadIdx.x;          // 1024 threads
    const int lane = tid & 63, wid = tid >> 6;
    if (tid == 0) s_base = 0;
    __syncthreads();
    for (int start = 0; start < n; start += 1024) {
        int i = start + tid;
        int v = (i < n) ? cnt[i] : 0;
        int x = v;
        #pragma unroll
        for (int d = 1; d < 64; d <<= 1) {
            int t = __shfl_up(x, d, 64);
            if (lane >= d) x += t;
        }
        if (lane == 63) wsum[wid] = x;
        __syncthreads();
        int wpref = 0;
        for (int w = 0; w < wid; ++w) wpref += wsum[w];
        int incl = wpref + x;
        int base = s_base;
        __syncthreads();
        if (i < n) { int e = base + incl - v; row_ptr[i] = e; cursor[i] = e; }
        if (tid == 1023) s_base = base + incl;
        __syncthreads();
    }
    if (threadIdx.x == 0) row_ptr[n] = s_base;
}

__global__ void k_fill(const int* __restrict__ src, const int* __restrict__ dst,
                       int* __restrict__ cursor, int* __restrict__ elist) {
    int e = blockIdx.x * 256 + threadIdx.x;
    if (e < NE) {
        int p = atomicAdd(&cursor[dst[e]], 1);
        elist[p] = src[e];
    }
}

// ---------------- GCN layer 1 ----------------
// t1 = feat @ gc1_W   [NN,128] @ [128,100]
__global__ void k_gemm1(const float* __restrict__ feat, const float* __restrict__ W,
                        float* __restrict__ t1) {
    __shared__ float sW[DIN * C1];      // 51200 B
    __shared__ float sf[2][DIN];
    for (int idx = threadIdx.x; idx < DIN * C1; idx += 256) sW[idx] = W[idx];
    const int sub = threadIdx.x >> 7;   // 0/1
    const int j = threadIdx.x & 127;
    for (int n0 = blockIdx.x * 2; n0 < NN; n0 += gridDim.x * 2) {
        __syncthreads();
        sf[sub][j] = feat[(n0 + sub) * DIN + j];
        __syncthreads();
        if (j < C1) {
            float acc = 0.f;
            #pragma unroll 8
            for (int k = 0; k < DIN; ++k) acc += sf[sub][k] * sW[k * C1 + j];
            t1[(n0 + sub) * C1 + j] = acc;
        }
    }
}

// h1 = relu(csr_mean(t1) + b)
__global__ void k_agg1(const float* __restrict__ t1, const int* __restrict__ row_ptr,
                       const int* __restrict__ elist, const int* __restrict__ cnt,
                       const float* __restrict__ bias, float* __restrict__ h1) {
    const int n = blockIdx.x;
    const int c = threadIdx.x;          // 128 threads, c<100 active
    if (c >= C1) return;
    int e0 = row_ptr[n], e1 = row_ptr[n + 1];
    float acc = 0.f;
    int e = e0;
    for (; e + 3 < e1; e += 4) {
        int s0 = elist[e], s1 = elist[e + 1], s2 = elist[e + 2], s3 = elist[e + 3];
        acc += t1[s0 * C1 + c];
        acc += t1[s1 * C1 + c];
        acc += t1[s2 * C1 + c];
        acc += t1[s3 * C1 + c];
    }
    for (; e < e1; ++e) acc += t1[elist[e] * C1 + c];
    float d = (float)cnt[n]; d = d > 1.f ? d : 1.f;
    float v = acc / d + bias[c];
    h1[n * C1 + c] = v > 0.f ? v : 0.f;
}

// ---------------- GCN layer 2 ----------------
// t2 = h1 @ gc2_W   [NN,100] @ [100,20]
__global__ void k_gemm2(const float* __restrict__ h1, const float* __restrict__ W,
                        float* __restrict__ t2) {
    __shared__ float sW[C1 * C2];       // 8000 B
    __shared__ float sr[16][C1];        // 6400 B
    for (int idx = threadIdx.x; idx < C1 * C2; idx += 320) sW[idx] = W[idx];
    int ln = threadIdx.x / C2, j = threadIdx.x % C2;   // ln<16
    int n0 = blockIdx.x * 16;
    __syncthreads();
    for (int idx = threadIdx.x; idx < 16 * C1; idx += 320) {
        int r = idx / C1, k = idx % C1;
        int n = n0 + r;
        sr[r][k] = (n < NN) ? h1[n * C1 + k] : 0.f;
    }
    __syncthreads();
    int n = n0 + ln;
    if (n < NN && ln < 16) {
        float acc = 0.f;
        #pragma unroll 4
        for (int k = 0; k < C1; ++k) acc += sr[ln][k] * sW[k * C2 + j];
        t2[n * C2 + j] = acc;
    }
}

__global__ void k_agg2(const float* __restrict__ t2, const int* __restrict__ row_ptr,
                       const int* __restrict__ elist, const int* __restrict__ cnt,
                       const float* __restrict__ bias, float* __restrict__ h2) {
    int ln = threadIdx.x / C2, c = threadIdx.x % C2;
    if (ln >= 12) return;
    int n = blockIdx.x * 12 + ln;
    if (n >= NN) return;
    int e0 = row_ptr[n], e1 = row_ptr[n + 1];
    float acc = 0.f;
    int e = e0;
    for (; e + 1 < e1; e += 2) {
        int s0 = elist[e], s1 = elist[e + 1];
        acc += t2[s0 * C2 + c];
        acc += t2[s1 * C2 + c];
    }
    for (; e < e1; ++e) acc += t2[elist[e] * C2 + c];
    float d = (float)cnt[n]; d = d > 1.f ? d : 1.f;
    float v = acc / d + bias[c];
    h2[n * C2 + c] = v > 0.f ? v : 0.f;
}

// ---------------- graph mean pool ----------------
__global__ void k_pool(const float* __restrict__ h2, const int* __restrict__ gid,
                       float* __restrict__ hgs) {
    int idx = blockIdx.x * 256 + threadIdx.x;
    if (idx < NN * C2) {
        int n = idx / C2, c = idx % C2;
        atomicAdd(&hgs[gid[n] * C2 + c], h2[idx]);
    }
}

__global__ void k_hgdiv(const float* __restrict__ hgs, const int* __restrict__ gcnt,
                        float* __restrict__ hg) {
    int idx = blockIdx.x * 256 + threadIdx.x;
    if (idx < NB * C2) {
        float d = (float)gcnt[idx / C2]; d = d > 1.f ? d : 1.f;
        hg[idx] = hgs[idx] / d;
    }
}

// ---------------- attention head: a = sigmoid(((hg@pgW+b)@W2) . (d2@p2W+b)) ----------------
__global__ void k_head(const float* __restrict__ hg, const float* __restrict__ desc2d,
                       const float* __restrict__ pgW, const float* __restrict__ pgb,
                       const float* __restrict__ p2W, const float* __restrict__ p2b,
                       const float* __restrict__ W2, float* __restrict__ a_out) {
    __shared__ float shg[C2];
    __shared__ float sg[DHH];
    int b = blockIdx.x, j = threadIdx.x;   // 64 threads
    if (j < C2) shg[j] = hg[b * C2 + j];
    __syncthreads();
    float hgj = pgb[j];
    #pragma unroll
    for (int k = 0; k < C2; ++k) hgj += shg[k] * pgW[k * DHH + j];
    float hdj = p2b[j];
    #pragma unroll 4
    for (int k = 0; k < DD2; ++k) hdj += desc2d[b * DD2 + k] * p2W[k * DHH + j];
    sg[j] = hgj;
    __syncthreads();
    float tj = 0.f;
    #pragma unroll 4
    for (int k = 0; k < DHH; ++k) tj += sg[k] * W2[k * DHH + j];
    float v = tj * hdj;
    #pragma unroll
    for (int off = 32; off; off >>= 1) v += __shfl_xor(v, off, 64);
    if (j == 0) a_out[b] = 1.f / (1.f + expf(-v));
}

// ---------------- fc1 over outer-product fusion (bias dropped: cancelled by BN) ----------------
// grid (32 b-tiles, 21 i), block 256. o1[b][j] += hg1[b][i] * sum_k d1[b][k]*W1[i*201+k][j]
__global__ void k_fc1(const float* __restrict__ hg, const float* __restrict__ desc2d,
                      const float* __restrict__ a, const float* __restrict__ W1,
                      float* __restrict__ o1) {
    __shared__ float S[16][DD2 + 1];    // 16 x 201
    const int i = blockIdx.y;           // 0..20
    const int bt = blockIdx.x;          // 0..31
    const int j = threadIdx.x & 127;
    const int h = threadIdx.x >> 7;
    for (int idx = threadIdx.x; idx < 16 * (DD2 + 1); idx += 256) {
        int bb = idx / (DD2 + 1), k = idx % (DD2 + 1);
        int b = bt * 16 + bb;
        float hgv = (i < C2) ? hg[b * C2 + i] : 1.f;
        float dv = (k < DD2) ? a[b] * desc2d[b * DD2 + k] : 1.f;
        S[bb][k] = hgv * dv;
    }
    __syncthreads();
    float acc[8] = {0.f, 0.f, 0.f, 0.f, 0.f, 0.f, 0.f, 0.f};
    const float* Wrow = W1 + (size_t)(i * (DD2 + 1)) * HH1 + j;
    #pragma unroll 2
    for (int k = 0; k < DD2 + 1; ++k) {
        float w = Wrow[(size_t)k * HH1];
        #pragma unroll
        for (int q = 0; q < 8; ++q) acc[q] += S[h * 8 + q][k] * w;
    }
    #pragma unroll
    for (int q = 0; q < 8; ++q) {
        int b = bt * 16 + h * 8 + q;
        atomicAdd(&o1[b * HH1 + j], acc[q]);
    }
}

// ---------------- batch-norm stats (mean + rstd per column) ----------------
__global__ void k_bnstats(const float* __restrict__ x, float* __restrict__ stats,
                          int ncols, int nrows) {
    int j = threadIdx.x;
    if (j < ncols) {
        float s = 0.f, s2 = 0.f;
        for (int b = 0; b < nrows; ++b) {
            float v = x[b * ncols + j];
            s += v; s2 += v * v;
        }
        float mu = s / nrows;
        float var = s2 / nrows - mu * mu;
        stats[j] = mu;
        stats[ncols + j] = rsqrtf(var + 1e-5f);
    }
}

// ---------------- fc2 (bn1 + relu fused in; fc2 bias dropped) ----------------
__global__ void k_fc2(const float* __restrict__ o1, const float* __restrict__ st1,
                      const float* __restrict__ g, const float* __restrict__ beta,
                      const float* __restrict__ W, float* __restrict__ o2) {
    __shared__ float r[HH1];
    __shared__ float part[4][HH2];
    int b = blockIdx.x;
    int tid = threadIdx.x;   // 128
    float v = o1[b * HH1 + tid];
    float nv = (v - st1[tid]) * st1[HH1 + tid] * g[tid] + beta[tid];
    r[tid] = fmaxf(nv, 0.f);
    __syncthreads();
    int m = tid & 31, p = tid >> 5;
    float acc = 0.f;
    #pragma unroll 4
    for (int j = p * 32; j < p * 32 + 32; ++j) acc += r[j] * W[j * HH2 + m];
    part[p][m] = acc;
    __syncthreads();
    if (tid < HH2) o2[b * HH2 + tid] = part[0][tid] + part[1][tid] + part[2][tid] + part[3][tid];
}

// ---------------- bn2 + relu + fc3 ----------------
__global__ void k_final(const float* __restrict__ o2, const float* __restrict__ st2,
                        const float* __restrict__ g, const float* __restrict__ beta,
                        const float* __restrict__ W3, const float* __restrict__ b3,
                        float* __restrict__ out) {
    int b = threadIdx.x;    // 512
    if (b < NB) {
        float acc = b3[0];
        #pragma unroll 4
        for (int m = 0; m < HH2; ++m) {
            float v = o2[b * HH2 + m];
            float nv = (v - st2[m]) * st2[HH2 + m] * g[m] + beta[m];
            acc += fmaxf(nv, 0.f) * W3[m];
        }
        out[b] = acc;
    }
}

extern "C" void kernel_launch(void* const* d_in, const int* in_sizes, int n_in,
                              void* d_out, int out_size, void* d_ws, size_t ws_size,
                              hipStream_t stream) {
    const float* feat   = (const float*)d_in[0];
    const float* desc2d = (const float*)d_in[1];
    const float* gc1W = (const float*)d_in[3];
    const float* gc1b = (const float*)d_in[4];
    const float* gc2W = (const float*)d_in[5];
    const float* gc2b = (const float*)d_in[6];
    const float* pgW  = (const float*)d_in[7];
    const float* pgb  = (const float*)d_in[8];
    const float* p2W  = (const float*)d_in[9];
    const float* p2b  = (const float*)d_in[10];
    const float* W2   = (const float*)d_in[11];
    const float* fc1W = (const float*)d_in[12];
    const float* fc2W = (const float*)d_in[14];
    const float* fc3W = (const float*)d_in[16];
    const float* fc3b = (const float*)d_in[17];
    const float* bn1g = (const float*)d_in[18];
    const float* bn1b = (const float*)d_in[19];
    const float* bn2g = (const float*)d_in[20];
    const float* bn2b = (const float*)d_in[21];
    const int* src = (const int*)d_in[22];
    const int* dst = (const int*)d_in[23];
    const int* gid = (const int*)d_in[24];
    float* out = (float*)d_out;

    char* ws = (char*)d_ws;
    size_t off = 0;
    auto alloc = [&](size_t nb) {
        void* p = ws + off;
        off = (off + nb + 255) & ~(size_t)255;
        return p;
    };
    float* t1    = (float*)alloc((size_t)NN * C1 * 4);
    float* h1    = (float*)alloc((size_t)NN * C1 * 4);
    int* cnt_in  = (int*)alloc((size_t)NN * 4);
    int* row_ptr = (int*)alloc((size_t)(NN + 1) * 4);
    int* cursor  = (int*)alloc((size_t)NN * 4);
    int* elist   = (int*)alloc((size_t)NE * 4);
    int* gcnt    = (int*)alloc((size_t)NB * 4);
    float* hgs   = (float*)alloc((size_t)NB * C2 * 4);
    float* hg    = (float*)alloc((size_t)NB * C2 * 4);
    float* avec  = (float*)alloc((size_t)NB * 4);
    float* o1    = (float*)alloc((size_t)NB * HH1 * 4);
    float* st1   = (float*)alloc(2 * HH1 * 4);
    float* o2    = (float*)alloc((size_t)NB * HH2 * 4);
    float* st2   = (float*)alloc(2 * HH2 * 4);
    float* t2 = t1;   // t1 dead after h1 computed
    float* h2 = h1;   // h1 dead after t2 computed

    hipMemsetAsync(cnt_in, 0, (size_t)NN * 4, stream);
    hipMemsetAsync(gcnt, 0, (size_t)NB * 4, stream);
    hipMemsetAsync(hgs, 0, (size_t)NB * C2 * 4, stream);
    hipMemsetAsync(o1, 0, (size_t)NB * HH1 * 4, stream);

    k_count<<<(NE + 255) / 256, 256, 0, stream>>>(dst, cnt_in);
    k_gcount<<<(NN + 255) / 256, 256, 0, stream>>>(gid, gcnt);
    k_scan<<<1, 1024, 0, stream>>>(cnt_in, row_ptr, cursor, NN);
    k_fill<<<(NE + 255) / 256, 256, 0, stream>>>(src, dst, cursor, elist);

    k_gemm1<<<1024, 256, 0, stream>>>(feat, gc1W, t1);
    k_agg1<<<NN, 128, 0, stream>>>(t1, row_ptr, elist, cnt_in, gc1b, h1);

    k_gemm2<<<(NN + 15) / 16, 320, 0, stream>>>(h1, gc2W, t2);
    k_agg2<<<(NN + 11) / 12, 256, 0, stream>>>(t2, row_ptr, elist, cnt_in, gc2b, h2);

    k_pool<<<(NN * C2 + 255) / 256, 256, 0, stream>>>(h2, gid, hgs);
    k_hgdiv<<<(NB * C2 + 255) / 256, 256, 0, stream>>>(hgs, gcnt, hg);

    k_head<<<NB, 64, 0, stream>>>(hg, desc2d, pgW, pgb, p2W, p2b, W2, avec);

    dim3 g1(32, 21);
    k_fc1<<<g1, 256, 0, stream>>>(hg, desc2d, avec, fc1W, o1);

    k_bnstats<<<1, 128, 0, stream>>>(o1, st1, HH1, NB);
    k_fc2<<<NB, 128, 0, stream>>>(o1, st1, bn1g, bn1b, fc2W, o2);
    k_bnstats<<<1, 64, 0, stream>>>(o2, st2, HH2, NB);
    k_final<<<1, 512, 0, stream>>>(o2, st2, bn2g, bn2b, fc3W, fc3b, out);
}

// Round 2
// 509.514 us; speedup vs baseline: 1.4240x; 1.4240x over previous
//
#include <hip/hip_runtime.h>

#define NN 50000
#define NE 800000
#define NB 512
#define DIN 128
#define DD2 200
#define C1 100
#define C2 20
#define DHH 64
#define HH1 128
#define HH2 32

// ---------------- CSR build ----------------
__global__ void k_count(const int* __restrict__ dst, int* __restrict__ cnt) {
    int e = blockIdx.x * 256 + threadIdx.x;
    if (e < NE) atomicAdd(&cnt[dst[e]], 1);
}

__global__ void k_gcount(const int* __restrict__ gid, int* __restrict__ gcnt) {
    int n = blockIdx.x * 256 + threadIdx.x;
    if (n < NN) atomicAdd(&gcnt[gid[n]], 1);
}

__global__ void k_scan(const int* __restrict__ cnt, int* __restrict__ row_ptr,
                       int* __restrict__ cursor, int n) {
    __shared__ int wsum[16];
    __shared__ int s_base;
    const int tid = threadIdx.x;          // 1024 threads
    const int lane = tid & 63, wid = tid >> 6;
    if (tid == 0) s_base = 0;
    __syncthreads();
    for (int start = 0; start < n; start += 1024) {
        int i = start + tid;
        int v = (i < n) ? cnt[i] : 0;
        int x = v;
        #pragma unroll
        for (int d = 1; d < 64; d <<= 1) {
            int t = __shfl_up(x, d, 64);
            if (lane >= d) x += t;
        }
        if (lane == 63) wsum[wid] = x;
        __syncthreads();
        int wpref = 0;
        for (int w = 0; w < wid; ++w) wpref += wsum[w];
        int incl = wpref + x;
        int base = s_base;
        __syncthreads();
        if (i < n) { int e = base + incl - v; row_ptr[i] = e; cursor[i] = e; }
        if (tid == 1023) s_base = base + incl;
        __syncthreads();
    }
    if (threadIdx.x == 0) row_ptr[n] = s_base;
}

__global__ void k_fill(const int* __restrict__ src, const int* __restrict__ dst,
                       int* __restrict__ cursor, int* __restrict__ elist) {
    int e = blockIdx.x * 256 + threadIdx.x;
    if (e < NE) {
        int p = atomicAdd(&cursor[dst[e]], 1);
        elist[p] = src[e];
    }
}

// ---------------- GCN layer 1 ----------------
// t1 = feat @ gc1_W   [NN,128] @ [128,100]
__global__ void k_gemm1(const float* __restrict__ feat, const float* __restrict__ W,
                        float* __restrict__ t1) {
    __shared__ float sW[DIN * C1];      // 51200 B
    __shared__ float sf[2][DIN];
    for (int idx = threadIdx.x; idx < DIN * C1; idx += 256) sW[idx] = W[idx];
    const int sub = threadIdx.x >> 7;   // 0/1
    const int j = threadIdx.x & 127;
    for (int n0 = blockIdx.x * 2; n0 < NN; n0 += gridDim.x * 2) {
        __syncthreads();
        sf[sub][j] = feat[(n0 + sub) * DIN + j];
        __syncthreads();
        if (j < C1) {
            float acc = 0.f;
            #pragma unroll 8
            for (int k = 0; k < DIN; ++k) acc += sf[sub][k] * sW[k * C1 + j];
            t1[(n0 + sub) * C1 + j] = acc;
        }
    }
}

// h1 = relu(csr_mean(t1) + b)
__global__ void k_agg1(const float* __restrict__ t1, const int* __restrict__ row_ptr,
                       const int* __restrict__ elist, const int* __restrict__ cnt,
                       const float* __restrict__ bias, float* __restrict__ h1) {
    const int n = blockIdx.x;
    const int c = threadIdx.x;          // 128 threads, c<100 active
    if (c >= C1) return;
    int e0 = row_ptr[n], e1 = row_ptr[n + 1];
    float acc = 0.f;
    int e = e0;
    for (; e + 3 < e1; e += 4) {
        int s0 = elist[e], s1 = elist[e + 1], s2 = elist[e + 2], s3 = elist[e + 3];
        acc += t1[s0 * C1 + c];
        acc += t1[s1 * C1 + c];
        acc += t1[s2 * C1 + c];
        acc += t1[s3 * C1 + c];
    }
    for (; e < e1; ++e) acc += t1[elist[e] * C1 + c];
    float d = (float)cnt[n]; d = d > 1.f ? d : 1.f;
    float v = acc / d + bias[c];
    h1[n * C1 + c] = v > 0.f ? v : 0.f;
}

// ---------------- GCN layer 2 ----------------
// t2 = h1 @ gc2_W   [NN,100] @ [100,20]
__global__ void k_gemm2(const float* __restrict__ h1, const float* __restrict__ W,
                        float* __restrict__ t2) {
    __shared__ float sW[C1 * C2];       // 8000 B
    __shared__ float sr[16][C1];        // 6400 B
    for (int idx = threadIdx.x; idx < C1 * C2; idx += 320) sW[idx] = W[idx];
    int ln = threadIdx.x / C2, j = threadIdx.x % C2;   // ln<16
    int n0 = blockIdx.x * 16;
    __syncthreads();
    for (int idx = threadIdx.x; idx < 16 * C1; idx += 320) {
        int r = idx / C1, k = idx % C1;
        int n = n0 + r;
        sr[r][k] = (n < NN) ? h1[n * C1 + k] : 0.f;
    }
    __syncthreads();
    int n = n0 + ln;
    if (n < NN && ln < 16) {
        float acc = 0.f;
        #pragma unroll 4
        for (int k = 0; k < C1; ++k) acc += sr[ln][k] * sW[k * C2 + j];
        t2[n * C2 + j] = acc;
    }
}

__global__ void k_agg2(const float* __restrict__ t2, const int* __restrict__ row_ptr,
                       const int* __restrict__ elist, const int* __restrict__ cnt,
                       const float* __restrict__ bias, float* __restrict__ h2) {
    int ln = threadIdx.x / C2, c = threadIdx.x % C2;
    if (ln >= 12) return;
    int n = blockIdx.x * 12 + ln;
    if (n >= NN) return;
    int e0 = row_ptr[n], e1 = row_ptr[n + 1];
    float acc = 0.f;
    int e = e0;
    for (; e + 1 < e1; e += 2) {
        int s0 = elist[e], s1 = elist[e + 1];
        acc += t2[s0 * C2 + c];
        acc += t2[s1 * C2 + c];
    }
    for (; e < e1; ++e) acc += t2[elist[e] * C2 + c];
    float d = (float)cnt[n]; d = d > 1.f ? d : 1.f;
    float v = acc / d + bias[c];
    h2[n * C2 + c] = v > 0.f ? v : 0.f;
}

// ---------------- graph mean pool ----------------
__global__ void k_pool(const float* __restrict__ h2, const int* __restrict__ gid,
                       float* __restrict__ hgs) {
    int idx = blockIdx.x * 256 + threadIdx.x;
    if (idx < NN * C2) {
        int n = idx / C2, c = idx % C2;
        atomicAdd(&hgs[gid[n] * C2 + c], h2[idx]);
    }
}

__global__ void k_hgdiv(const float* __restrict__ hgs, const int* __restrict__ gcnt,
                        float* __restrict__ hg) {
    int idx = blockIdx.x * 256 + threadIdx.x;
    if (idx < NB * C2) {
        float d = (float)gcnt[idx / C2]; d = d > 1.f ? d : 1.f;
        hg[idx] = hgs[idx] / d;
    }
}

// ---------------- attention head: a = sigmoid(((hg@pgW+b)@W2) . (d2@p2W+b)) ----------------
__global__ void k_head(const float* __restrict__ hg, const float* __restrict__ desc2d,
                       const float* __restrict__ pgW, const float* __restrict__ pgb,
                       const float* __restrict__ p2W, const float* __restrict__ p2b,
                       const float* __restrict__ W2, float* __restrict__ a_out) {
    __shared__ float shg[C2];
    __shared__ float sg[DHH];
    int b = blockIdx.x, j = threadIdx.x;   // 64 threads
    if (j < C2) shg[j] = hg[b * C2 + j];
    __syncthreads();
    float hgj = pgb[j];
    #pragma unroll
    for (int k = 0; k < C2; ++k) hgj += shg[k] * pgW[k * DHH + j];
    float hdj = p2b[j];
    #pragma unroll 4
    for (int k = 0; k < DD2; ++k) hdj += desc2d[b * DD2 + k] * p2W[k * DHH + j];
    sg[j] = hgj;
    __syncthreads();
    float tj = 0.f;
    #pragma unroll 4
    for (int k = 0; k < DHH; ++k) tj += sg[k] * W2[k * DHH + j];
    float v = tj * hdj;
    #pragma unroll
    for (int off = 32; off; off >>= 1) v += __shfl_xor(v, off, 64);
    if (j == 0) a_out[b] = 1.f / (1.f + expf(-v));
}

// ---------------- fc1 over outer-product fusion (bias dropped: cancelled by BN) ----------------
// grid (32 b-tiles, 21 i), block 256. o1[b][j] += hg1[b][i] * sum_k d1[b][k]*W1[i*201+k][j]
__global__ void k_fc1(const float* __restrict__ hg, const float* __restrict__ desc2d,
                      const float* __restrict__ a, const float* __restrict__ W1,
                      float* __restrict__ o1) {
    __shared__ float S[16][DD2 + 1];    // 16 x 201
    const int i = blockIdx.y;           // 0..20
    const int bt = blockIdx.x;          // 0..31
    const int j = threadIdx.x & 127;
    const int h = threadIdx.x >> 7;
    for (int idx = threadIdx.x; idx < 16 * (DD2 + 1); idx += 256) {
        int bb = idx / (DD2 + 1), k = idx % (DD2 + 1);
        int b = bt * 16 + bb;
        float hgv = (i < C2) ? hg[b * C2 + i] : 1.f;
        float dv = (k < DD2) ? a[b] * desc2d[b * DD2 + k] : 1.f;
        S[bb][k] = hgv * dv;
    }
    __syncthreads();
    float acc[8] = {0.f, 0.f, 0.f, 0.f, 0.f, 0.f, 0.f, 0.f};
    const float* Wrow = W1 + (size_t)(i * (DD2 + 1)) * HH1 + j;
    #pragma unroll 2
    for (int k = 0; k < DD2 + 1; ++k) {
        float w = Wrow[(size_t)k * HH1];
        #pragma unroll
        for (int q = 0; q < 8; ++q) acc[q] += S[h * 8 + q][k] * w;
    }
    #pragma unroll
    for (int q = 0; q < 8; ++q) {
        int b = bt * 16 + h * 8 + q;
        atomicAdd(&o1[b * HH1 + j], acc[q]);
    }
}

// ---------------- batch-norm stats (mean + rstd per column), row-parallel ----------------
// 1024 threads = ncols * R; coalesced loads; LDS tree reduce over R partials.
__global__ void k_bnstats(const float* __restrict__ x, float* __restrict__ stats,
                          int ncols, int nrows) {
    __shared__ float sh[1024], sh2[1024];
    const int tid = threadIdx.x;
    const int j = tid % ncols;
    const int r = tid / ncols;
    const int R = 1024 / ncols;
    float s = 0.f, s2 = 0.f;
    for (int b = r; b < nrows; b += R) {
        float v = x[b * ncols + j];
        s += v; s2 += v * v;
    }
    sh[tid] = s; sh2[tid] = s2;
    __syncthreads();
    if (r == 0) {
        for (int q = 1; q < R; ++q) { s += sh[q * ncols + j]; s2 += sh2[q * ncols + j]; }
        float mu = s / nrows;
        float var = s2 / nrows - mu * mu;
        stats[j] = mu;
        stats[ncols + j] = rsqrtf(var + 1e-5f);
    }
}

// ---------------- fc2 (bn1 + relu fused in; fc2 bias dropped) ----------------
__global__ void k_fc2(const float* __restrict__ o1, const float* __restrict__ st1,
                      const float* __restrict__ g, const float* __restrict__ beta,
                      const float* __restrict__ W, float* __restrict__ o2) {
    __shared__ float r[HH1];
    __shared__ float part[4][HH2];
    int b = blockIdx.x;
    int tid = threadIdx.x;   // 128
    float v = o1[b * HH1 + tid];
    float nv = (v - st1[tid]) * st1[HH1 + tid] * g[tid] + beta[tid];
    r[tid] = fmaxf(nv, 0.f);
    __syncthreads();
    int m = tid & 31, p = tid >> 5;
    float acc = 0.f;
    #pragma unroll 4
    for (int j = p * 32; j < p * 32 + 32; ++j) acc += r[j] * W[j * HH2 + m];
    part[p][m] = acc;
    __syncthreads();
    if (tid < HH2) o2[b * HH2 + tid] = part[0][tid] + part[1][tid] + part[2][tid] + part[3][tid];
}

// ---------------- bn2 + relu + fc3 ----------------
__global__ void k_final(const float* __restrict__ o2, const float* __restrict__ st2,
                        const float* __restrict__ g, const float* __restrict__ beta,
                        const float* __restrict__ W3, const float* __restrict__ b3,
                        float* __restrict__ out) {
    int b = threadIdx.x;    // 512
    if (b < NB) {
        float acc = b3[0];
        #pragma unroll 4
        for (int m = 0; m < HH2; ++m) {
            float v = o2[b * HH2 + m];
            float nv = (v - st2[m]) * st2[HH2 + m] * g[m] + beta[m];
            acc += fmaxf(nv, 0.f) * W3[m];
        }
        out[b] = acc;
    }
}

extern "C" void kernel_launch(void* const* d_in, const int* in_sizes, int n_in,
                              void* d_out, int out_size, void* d_ws, size_t ws_size,
                              hipStream_t stream) {
    const float* feat   = (const float*)d_in[0];
    const float* desc2d = (const float*)d_in[1];
    const float* gc1W = (const float*)d_in[3];
    const float* gc1b = (const float*)d_in[4];
    const float* gc2W = (const float*)d_in[5];
    const float* gc2b = (const float*)d_in[6];
    const float* pgW  = (const float*)d_in[7];
    const float* pgb  = (const float*)d_in[8];
    const float* p2W  = (const float*)d_in[9];
    const float* p2b  = (const float*)d_in[10];
    const float* W2   = (const float*)d_in[11];
    const float* fc1W = (const float*)d_in[12];
    const float* fc2W = (const float*)d_in[14];
    const float* fc3W = (const float*)d_in[16];
    const float* fc3b = (const float*)d_in[17];
    const float* bn1g = (const float*)d_in[18];
    const float* bn1b = (const float*)d_in[19];
    const float* bn2g = (const float*)d_in[20];
    const float* bn2b = (const float*)d_in[21];
    const int* src = (const int*)d_in[22];
    const int* dst = (const int*)d_in[23];
    const int* gid = (const int*)d_in[24];
    float* out = (float*)d_out;

    char* ws = (char*)d_ws;
    size_t off = 0;
    auto alloc = [&](size_t nb) {
        void* p = ws + off;
        off = (off + nb + 255) & ~(size_t)255;
        return p;
    };
    float* t1    = (float*)alloc((size_t)NN * C1 * 4);
    float* h1    = (float*)alloc((size_t)NN * C1 * 4);
    int* cnt_in  = (int*)alloc((size_t)NN * 4);
    int* row_ptr = (int*)alloc((size_t)(NN + 1) * 4);
    int* cursor  = (int*)alloc((size_t)NN * 4);
    int* elist   = (int*)alloc((size_t)NE * 4);
    int* gcnt    = (int*)alloc((size_t)NB * 4);
    float* hgs   = (float*)alloc((size_t)NB * C2 * 4);
    float* hg    = (float*)alloc((size_t)NB * C2 * 4);
    float* avec  = (float*)alloc((size_t)NB * 4);
    float* o1    = (float*)alloc((size_t)NB * HH1 * 4);
    float* st1   = (float*)alloc(2 * HH1 * 4);
    float* o2    = (float*)alloc((size_t)NB * HH2 * 4);
    float* st2   = (float*)alloc(2 * HH2 * 4);
    float* t2 = t1;   // t1 dead after h1 computed
    float* h2 = h1;   // h1 dead after t2 computed

    hipMemsetAsync(cnt_in, 0, (size_t)NN * 4, stream);
    hipMemsetAsync(gcnt, 0, (size_t)NB * 4, stream);
    hipMemsetAsync(hgs, 0, (size_t)NB * C2 * 4, stream);
    hipMemsetAsync(o1, 0, (size_t)NB * HH1 * 4, stream);

    k_count<<<(NE + 255) / 256, 256, 0, stream>>>(dst, cnt_in);
    k_gcount<<<(NN + 255) / 256, 256, 0, stream>>>(gid, gcnt);
    k_scan<<<1, 1024, 0, stream>>>(cnt_in, row_ptr, cursor, NN);
    k_fill<<<(NE + 255) / 256, 256, 0, stream>>>(src, dst, cursor, elist);

    k_gemm1<<<1024, 256, 0, stream>>>(feat, gc1W, t1);
    k_agg1<<<NN, 128, 0, stream>>>(t1, row_ptr, elist, cnt_in, gc1b, h1);

    k_gemm2<<<(NN + 15) / 16, 320, 0, stream>>>(h1, gc2W, t2);
    k_agg2<<<(NN + 11) / 12, 256, 0, stream>>>(t2, row_ptr, elist, cnt_in, gc2b, h2);

    k_pool<<<(NN * C2 + 255) / 256, 256, 0, stream>>>(h2, gid, hgs);
    k_hgdiv<<<(NB * C2 + 255) / 256, 256, 0, stream>>>(hgs, gcnt, hg);

    k_head<<<NB, 64, 0, stream>>>(hg, desc2d, pgW, pgb, p2W, p2b, W2, avec);

    dim3 g1(32, 21);
    k_fc1<<<g1, 256, 0, stream>>>(hg, desc2d, avec, fc1W, o1);

    k_bnstats<<<1, 1024, 0, stream>>>(o1, st1, HH1, NB);
    k_fc2<<<NB, 128, 0, stream>>>(o1, st1, bn1g, bn1b, fc2W, o2);
    k_bnstats<<<1, 1024, 0, stream>>>(o2, st2, HH2, NB);
    k_final<<<1, 512, 0, stream>>>(o2, st2, bn2g, bn2b, fc3W, fc3b, out);
}

// Round 3
// 455.676 us; speedup vs baseline: 1.5922x; 1.1182x over previous
//
#include <hip/hip_runtime.h>

#define NN 50000
#define NE 800000
#define NB 512
#define DIN 128
#define DD2 200
#define C1 100
#define C2 20
#define DHH 64
#define HH1 128
#define HH2 32

// ---------------- CSR build ----------------
__global__ void k_count(const int* __restrict__ dst, int* __restrict__ cnt) {
    int e = blockIdx.x * 256 + threadIdx.x;
    if (e < NE) atomicAdd(&cnt[dst[e]], 1);
}

__global__ void k_gcount(const int* __restrict__ gid, int* __restrict__ gcnt) {
    int n = blockIdx.x * 256 + threadIdx.x;
    if (n < NN) atomicAdd(&gcnt[gid[n]], 1);
}

__global__ void k_scan(const int* __restrict__ cnt, int* __restrict__ row_ptr,
                       int* __restrict__ cursor, int n) {
    __shared__ int wsum[16];
    __shared__ int s_base;
    const int tid = threadIdx.x;          // 1024 threads
    const int lane = tid & 63, wid = tid >> 6;
    if (tid == 0) s_base = 0;
    __syncthreads();
    for (int start = 0; start < n; start += 1024) {
        int i = start + tid;
        int v = (i < n) ? cnt[i] : 0;
        int x = v;
        #pragma unroll
        for (int d = 1; d < 64; d <<= 1) {
            int t = __shfl_up(x, d, 64);
            if (lane >= d) x += t;
        }
        if (lane == 63) wsum[wid] = x;
        __syncthreads();
        int wpref = 0;
        for (int w = 0; w < wid; ++w) wpref += wsum[w];
        int incl = wpref + x;
        int base = s_base;
        __syncthreads();
        if (i < n) { int e = base + incl - v; row_ptr[i] = e; cursor[i] = e; }
        if (tid == 1023) s_base = base + incl;
        __syncthreads();
    }
    if (threadIdx.x == 0) row_ptr[n] = s_base;
}

__global__ void k_fill(const int* __restrict__ src, const int* __restrict__ dst,
                       int* __restrict__ cursor, int* __restrict__ elist) {
    int e = blockIdx.x * 256 + threadIdx.x;
    if (e < NE) {
        int p = atomicAdd(&cursor[dst[e]], 1);
        elist[p] = src[e];
    }
}

// ---------------- GCN layer 1 ----------------
// t1 = feat @ gc1_W   [NN,128] @ [128,100]
// Register-tiled: thread = (col pair j/j+50, row group rg of 8). 32 rows/iter.
// Weights transposed+swizzled in LDS: read b128, all 32 banks covered.
__global__ __launch_bounds__(256, 2) void k_gemm1(const float* __restrict__ feat,
                                                  const float* __restrict__ W,
                                                  float* __restrict__ t1) {
    __shared__ float sWT[C1 * DIN];      // 51.2 KB  sWT[col*128 + (k ^ ((col&7)<<2))]
    __shared__ float sf[32][DIN + 4];    // 16.9 KB  padded rows
    const int tid = threadIdx.x;
    for (int idx = tid; idx < DIN * C1; idx += 256) {
        int k = idx / C1, col = idx % C1;
        sWT[col * DIN + (k ^ ((col & 7) << 2))] = W[idx];
    }
    const int j = tid & 63;              // active j<50: cols j, j+50
    const int rg = tid >> 6;             // 0..3
    const bool act = j < 50;
    const int c0 = j, c1 = j + 50;
    const int swz0 = (c0 & 7) << 2, swz1 = (c1 & 7) << 2;

    for (int n0 = blockIdx.x * 32; n0 < NN; n0 += gridDim.x * 32) {
        __syncthreads();
        {   // stage 32 feat rows, 16 floats per thread
            int r = tid >> 3, so = (tid & 7) * 16;
            int n = n0 + r;
            float4* dstp = (float4*)&sf[r][so];
            if (n < NN) {
                const float4* srcp = (const float4*)(feat + (size_t)n * DIN + so);
                dstp[0] = srcp[0]; dstp[1] = srcp[1]; dstp[2] = srcp[2]; dstp[3] = srcp[3];
            } else {
                float4 z = {0.f, 0.f, 0.f, 0.f};
                dstp[0] = z; dstp[1] = z; dstp[2] = z; dstp[3] = z;
            }
        }
        __syncthreads();
        if (act) {
            float acc0[8], acc1[8];
            #pragma unroll
            for (int r = 0; r < 8; ++r) { acc0[r] = 0.f; acc1[r] = 0.f; }
            #pragma unroll 4
            for (int kc = 0; kc < DIN; kc += 4) {
                float4 w0 = *(const float4*)&sWT[c0 * DIN + (kc ^ swz0)];
                float4 w1 = *(const float4*)&sWT[c1 * DIN + (kc ^ swz1)];
                #pragma unroll
                for (int r = 0; r < 8; ++r) {
                    float4 a = *(const float4*)&sf[rg * 8 + r][kc];
                    acc0[r] += a.x * w0.x; acc0[r] += a.y * w0.y;
                    acc0[r] += a.z * w0.z; acc0[r] += a.w * w0.w;
                    acc1[r] += a.x * w1.x; acc1[r] += a.y * w1.y;
                    acc1[r] += a.z * w1.z; acc1[r] += a.w * w1.w;
                }
            }
            #pragma unroll
            for (int r = 0; r < 8; ++r) {
                int n = n0 + rg * 8 + r;
                if (n < NN) {
                    t1[(size_t)n * C1 + c0] = acc0[r];
                    t1[(size_t)n * C1 + c1] = acc1[r];
                }
            }
        }
    }
}

// h1 = relu(csr_mean(t1) + b)
__global__ void k_agg1(const float* __restrict__ t1, const int* __restrict__ row_ptr,
                       const int* __restrict__ elist, const int* __restrict__ cnt,
                       const float* __restrict__ bias, float* __restrict__ h1) {
    const int n = blockIdx.x;
    const int c = threadIdx.x;          // 128 threads, c<100 active
    if (c >= C1) return;
    int e0 = row_ptr[n], e1 = row_ptr[n + 1];
    float acc = 0.f;
    int e = e0;
    for (; e + 3 < e1; e += 4) {
        int s0 = elist[e], s1 = elist[e + 1], s2 = elist[e + 2], s3 = elist[e + 3];
        acc += t1[s0 * C1 + c];
        acc += t1[s1 * C1 + c];
        acc += t1[s2 * C1 + c];
        acc += t1[s3 * C1 + c];
    }
    for (; e < e1; ++e) acc += t1[elist[e] * C1 + c];
    float d = (float)cnt[n]; d = d > 1.f ? d : 1.f;
    float v = acc / d + bias[c];
    h1[n * C1 + c] = v > 0.f ? v : 0.f;
}

// ---------------- GCN layer 2 ----------------
// t2 = h1 @ gc2_W   [NN,100] @ [100,20]
__global__ void k_gemm2(const float* __restrict__ h1, const float* __restrict__ W,
                        float* __restrict__ t2) {
    __shared__ float sW[C1 * C2];       // 8000 B
    __shared__ float sr[16][C1];        // 6400 B
    for (int idx = threadIdx.x; idx < C1 * C2; idx += 320) sW[idx] = W[idx];
    int ln = threadIdx.x / C2, j = threadIdx.x % C2;   // ln<16
    int n0 = blockIdx.x * 16;
    __syncthreads();
    for (int idx = threadIdx.x; idx < 16 * C1; idx += 320) {
        int r = idx / C1, k = idx % C1;
        int n = n0 + r;
        sr[r][k] = (n < NN) ? h1[n * C1 + k] : 0.f;
    }
    __syncthreads();
    int n = n0 + ln;
    if (n < NN && ln < 16) {
        float acc = 0.f;
        #pragma unroll 4
        for (int k = 0; k < C1; ++k) acc += sr[ln][k] * sW[k * C2 + j];
        t2[n * C2 + j] = acc;
    }
}

__global__ void k_agg2(const float* __restrict__ t2, const int* __restrict__ row_ptr,
                       const int* __restrict__ elist, const int* __restrict__ cnt,
                       const float* __restrict__ bias, float* __restrict__ h2) {
    int ln = threadIdx.x / C2, c = threadIdx.x % C2;
    if (ln >= 12) return;
    int n = blockIdx.x * 12 + ln;
    if (n >= NN) return;
    int e0 = row_ptr[n], e1 = row_ptr[n + 1];
    float acc = 0.f;
    int e = e0;
    for (; e + 1 < e1; e += 2) {
        int s0 = elist[e], s1 = elist[e + 1];
        acc += t2[s0 * C2 + c];
        acc += t2[s1 * C2 + c];
    }
    for (; e < e1; ++e) acc += t2[elist[e] * C2 + c];
    float d = (float)cnt[n]; d = d > 1.f ? d : 1.f;
    float v = acc / d + bias[c];
    h2[n * C2 + c] = v > 0.f ? v : 0.f;
}

// ---------------- graph mean pool ----------------
__global__ void k_pool(const float* __restrict__ h2, const int* __restrict__ gid,
                       float* __restrict__ hgs) {
    int idx = blockIdx.x * 256 + threadIdx.x;
    if (idx < NN * C2) {
        int n = idx / C2, c = idx % C2;
        atomicAdd(&hgs[gid[n] * C2 + c], h2[idx]);
    }
}

__global__ void k_hgdiv(const float* __restrict__ hgs, const int* __restrict__ gcnt,
                        float* __restrict__ hg) {
    int idx = blockIdx.x * 256 + threadIdx.x;
    if (idx < NB * C2) {
        float d = (float)gcnt[idx / C2]; d = d > 1.f ? d : 1.f;
        hg[idx] = hgs[idx] / d;
    }
}

// ---------------- attention head: a = sigmoid(((hg@pgW+b)@W2) . (d2@p2W+b)) ----------------
__global__ void k_head(const float* __restrict__ hg, const float* __restrict__ desc2d,
                       const float* __restrict__ pgW, const float* __restrict__ pgb,
                       const float* __restrict__ p2W, const float* __restrict__ p2b,
                       const float* __restrict__ W2, float* __restrict__ a_out) {
    __shared__ float shg[C2];
    __shared__ float sg[DHH];
    int b = blockIdx.x, j = threadIdx.x;   // 64 threads
    if (j < C2) shg[j] = hg[b * C2 + j];
    __syncthreads();
    float hgj = pgb[j];
    #pragma unroll
    for (int k = 0; k < C2; ++k) hgj += shg[k] * pgW[k * DHH + j];
    float hdj = p2b[j];
    #pragma unroll 4
    for (int k = 0; k < DD2; ++k) hdj += desc2d[b * DD2 + k] * p2W[k * DHH + j];
    sg[j] = hgj;
    __syncthreads();
    float tj = 0.f;
    #pragma unroll 4
    for (int k = 0; k < DHH; ++k) tj += sg[k] * W2[k * DHH + j];
    float v = tj * hdj;
    #pragma unroll
    for (int off = 32; off; off >>= 1) v += __shfl_xor(v, off, 64);
    if (j == 0) a_out[b] = 1.f / (1.f + expf(-v));
}

// ---------------- fc1 over outer-product fusion (bias dropped: cancelled by BN) ----------------
// grid (32 b-tiles, 21 i), block 256. o1[b][j] += hg1[b][i] * sum_k d1[b][k]*W1[i*201+k][j]
__global__ void k_fc1(const float* __restrict__ hg, const float* __restrict__ desc2d,
                      const float* __restrict__ a, const float* __restrict__ W1,
                      float* __restrict__ o1) {
    __shared__ float S[16][DD2 + 1];    // 16 x 201
    const int i = blockIdx.y;           // 0..20
    const int bt = blockIdx.x;          // 0..31
    const int j = threadIdx.x & 127;
    const int h = threadIdx.x >> 7;
    for (int idx = threadIdx.x; idx < 16 * (DD2 + 1); idx += 256) {
        int bb = idx / (DD2 + 1), k = idx % (DD2 + 1);
        int b = bt * 16 + bb;
        float hgv = (i < C2) ? hg[b * C2 + i] : 1.f;
        float dv = (k < DD2) ? a[b] * desc2d[b * DD2 + k] : 1.f;
        S[bb][k] = hgv * dv;
    }
    __syncthreads();
    float acc[8] = {0.f, 0.f, 0.f, 0.f, 0.f, 0.f, 0.f, 0.f};
    const float* Wrow = W1 + (size_t)(i * (DD2 + 1)) * HH1 + j;
    #pragma unroll 2
    for (int k = 0; k < DD2 + 1; ++k) {
        float w = Wrow[(size_t)k * HH1];
        #pragma unroll
        for (int q = 0; q < 8; ++q) acc[q] += S[h * 8 + q][k] * w;
    }
    #pragma unroll
    for (int q = 0; q < 8; ++q) {
        int b = bt * 16 + h * 8 + q;
        atomicAdd(&o1[b * HH1 + j], acc[q]);
    }
}

// ---------------- batch-norm stats (mean + rstd per column), row-parallel ----------------
__global__ void k_bnstats(const float* __restrict__ x, float* __restrict__ stats,
                          int ncols, int nrows) {
    __shared__ float sh[1024], sh2[1024];
    const int tid = threadIdx.x;
    const int j = tid % ncols;
    const int r = tid / ncols;
    const int R = 1024 / ncols;
    float s = 0.f, s2 = 0.f;
    for (int b = r; b < nrows; b += R) {
        float v = x[b * ncols + j];
        s += v; s2 += v * v;
    }
    sh[tid] = s; sh2[tid] = s2;
    __syncthreads();
    if (r == 0) {
        for (int q = 1; q < R; ++q) { s += sh[q * ncols + j]; s2 += sh2[q * ncols + j]; }
        float mu = s / nrows;
        float var = s2 / nrows - mu * mu;
        stats[j] = mu;
        stats[ncols + j] = rsqrtf(var + 1e-5f);
    }
}

// ---------------- fc2 (bn1 + relu fused in; fc2 bias dropped) ----------------
__global__ void k_fc2(const float* __restrict__ o1, const float* __restrict__ st1,
                      const float* __restrict__ g, const float* __restrict__ beta,
                      const float* __restrict__ W, float* __restrict__ o2) {
    __shared__ float r[HH1];
    __shared__ float part[4][HH2];
    int b = blockIdx.x;
    int tid = threadIdx.x;   // 128
    float v = o1[b * HH1 + tid];
    float nv = (v - st1[tid]) * st1[HH1 + tid] * g[tid] + beta[tid];
    r[tid] = fmaxf(nv, 0.f);
    __syncthreads();
    int m = tid & 31, p = tid >> 5;
    float acc = 0.f;
    #pragma unroll 4
    for (int j = p * 32; j < p * 32 + 32; ++j) acc += r[j] * W[j * HH2 + m];
    part[p][m] = acc;
    __syncthreads();
    if (tid < HH2) o2[b * HH2 + tid] = part[0][tid] + part[1][tid] + part[2][tid] + part[3][tid];
}

// ---------------- bn2 + relu + fc3 ----------------
__global__ void k_final(const float* __restrict__ o2, const float* __restrict__ st2,
                        const float* __restrict__ g, const float* __restrict__ beta,
                        const float* __restrict__ W3, const float* __restrict__ b3,
                        float* __restrict__ out) {
    int b = threadIdx.x;    // 512
    if (b < NB) {
        float acc = b3[0];
        #pragma unroll 4
        for (int m = 0; m < HH2; ++m) {
            float v = o2[b * HH2 + m];
            float nv = (v - st2[m]) * st2[HH2 + m] * g[m] + beta[m];
            acc += fmaxf(nv, 0.f) * W3[m];
        }
        out[b] = acc;
    }
}

extern "C" void kernel_launch(void* const* d_in, const int* in_sizes, int n_in,
                              void* d_out, int out_size, void* d_ws, size_t ws_size,
                              hipStream_t stream) {
    const float* feat   = (const float*)d_in[0];
    const float* desc2d = (const float*)d_in[1];
    const float* gc1W = (const float*)d_in[3];
    const float* gc1b = (const float*)d_in[4];
    const float* gc2W = (const float*)d_in[5];
    const float* gc2b = (const float*)d_in[6];
    const float* pgW  = (const float*)d_in[7];
    const float* pgb  = (const float*)d_in[8];
    const float* p2W  = (const float*)d_in[9];
    const float* p2b  = (const float*)d_in[10];
    const float* W2   = (const float*)d_in[11];
    const float* fc1W = (const float*)d_in[12];
    const float* fc2W = (const float*)d_in[14];
    const float* fc3W = (const float*)d_in[16];
    const float* fc3b = (const float*)d_in[17];
    const float* bn1g = (const float*)d_in[18];
    const float* bn1b = (const float*)d_in[19];
    const float* bn2g = (const float*)d_in[20];
    const float* bn2b = (const float*)d_in[21];
    const int* src = (const int*)d_in[22];
    const int* dst = (const int*)d_in[23];
    const int* gid = (const int*)d_in[24];
    float* out = (float*)d_out;

    char* ws = (char*)d_ws;
    size_t off = 0;
    auto alloc = [&](size_t nb) {
        void* p = ws + off;
        off = (off + nb + 255) & ~(size_t)255;
        return p;
    };
    float* t1    = (float*)alloc((size_t)NN * C1 * 4);
    float* h1    = (float*)alloc((size_t)NN * C1 * 4);
    int* cnt_in  = (int*)alloc((size_t)NN * 4);
    int* row_ptr = (int*)alloc((size_t)(NN + 1) * 4);
    int* cursor  = (int*)alloc((size_t)NN * 4);
    int* elist   = (int*)alloc((size_t)NE * 4);
    int* gcnt    = (int*)alloc((size_t)NB * 4);
    float* hgs   = (float*)alloc((size_t)NB * C2 * 4);
    float* hg    = (float*)alloc((size_t)NB * C2 * 4);
    float* avec  = (float*)alloc((size_t)NB * 4);
    float* o1    = (float*)alloc((size_t)NB * HH1 * 4);
    float* st1   = (float*)alloc(2 * HH1 * 4);
    float* o2    = (float*)alloc((size_t)NB * HH2 * 4);
    float* st2   = (float*)alloc(2 * HH2 * 4);
    float* t2 = t1;   // t1 dead after h1 computed
    float* h2 = h1;   // h1 dead after t2 computed

    hipMemsetAsync(cnt_in, 0, (size_t)NN * 4, stream);
    hipMemsetAsync(gcnt, 0, (size_t)NB * 4, stream);
    hipMemsetAsync(hgs, 0, (size_t)NB * C2 * 4, stream);
    hipMemsetAsync(o1, 0, (size_t)NB * HH1 * 4, stream);

    k_count<<<(NE + 255) / 256, 256, 0, stream>>>(dst, cnt_in);
    k_gcount<<<(NN + 255) / 256, 256, 0, stream>>>(gid, gcnt);
    k_scan<<<1, 1024, 0, stream>>>(cnt_in, row_ptr, cursor, NN);
    k_fill<<<(NE + 255) / 256, 256, 0, stream>>>(src, dst, cursor, elist);

    k_gemm1<<<512, 256, 0, stream>>>(feat, gc1W, t1);
    k_agg1<<<NN, 128, 0, stream>>>(t1, row_ptr, elist, cnt_in, gc1b, h1);

    k_gemm2<<<(NN + 15) / 16, 320, 0, stream>>>(h1, gc2W, t2);
    k_agg2<<<(NN + 11) / 12, 256, 0, stream>>>(t2, row_ptr, elist, cnt_in, gc2b, h2);

    k_pool<<<(NN * C2 + 255) / 256, 256, 0, stream>>>(h2, gid, hgs);
    k_hgdiv<<<(NB * C2 + 255) / 256, 256, 0, stream>>>(hgs, gcnt, hg);

    k_head<<<NB, 64, 0, stream>>>(hg, desc2d, pgW, pgb, p2W, p2b, W2, avec);

    dim3 g1(32, 21);
    k_fc1<<<g1, 256, 0, stream>>>(hg, desc2d, avec, fc1W, o1);

    k_bnstats<<<1, 1024, 0, stream>>>(o1, st1, HH1, NB);
    k_fc2<<<NB, 128, 0, stream>>>(o1, st1, bn1g, bn1b, fc2W, o2);
    k_bnstats<<<1, 1024, 0, stream>>>(o2, st2, HH2, NB);
    k_final<<<1, 512, 0, stream>>>(o2, st2, bn2g, bn2b, fc3W, fc3b, out);
}

// Round 4
// 429.190 us; speedup vs baseline: 1.6905x; 1.0617x over previous
//
#include <hip/hip_runtime.h>

#define NN 50000
#define NE 800000
#define NB 512
#define DIN 128
#define DD2 200
#define C1 100
#define C2 20
#define DHH 64
#define HH1 128
#define HH2 32
#define KD 201      // fusion inner dim per i (200 + 1)
#define KDP 204     // padded row stride for d1ext
#define NU 2688     // 21 * 128

// ---------------- CSR build ----------------
__global__ void k_count(const int* __restrict__ dst, int* __restrict__ cnt) {
    int e = blockIdx.x * 256 + threadIdx.x;
    if (e < NE) atomicAdd(&cnt[dst[e]], 1);
}

__global__ void k_gcount(const int* __restrict__ gid, int* __restrict__ gcnt) {
    int n = blockIdx.x * 256 + threadIdx.x;
    if (n < NN) atomicAdd(&gcnt[gid[n]], 1);
}

__global__ void k_scan(const int* __restrict__ cnt, int* __restrict__ row_ptr,
                       int* __restrict__ cursor, int n) {
    __shared__ int wsum[16];
    __shared__ int s_base;
    const int tid = threadIdx.x;          // 1024 threads
    const int lane = tid & 63, wid = tid >> 6;
    if (tid == 0) s_base = 0;
    __syncthreads();
    for (int start = 0; start < n; start += 1024) {
        int i = start + tid;
        int v = (i < n) ? cnt[i] : 0;
        int x = v;
        #pragma unroll
        for (int d = 1; d < 64; d <<= 1) {
            int t = __shfl_up(x, d, 64);
            if (lane >= d) x += t;
        }
        if (lane == 63) wsum[wid] = x;
        __syncthreads();
        int wpref = 0;
        for (int w = 0; w < wid; ++w) wpref += wsum[w];
        int incl = wpref + x;
        int base = s_base;
        __syncthreads();
        if (i < n) { int e = base + incl - v; row_ptr[i] = e; cursor[i] = e; }
        if (tid == 1023) s_base = base + incl;
        __syncthreads();
    }
    if (threadIdx.x == 0) row_ptr[n] = s_base;
}

__global__ void k_fill(const int* __restrict__ src, const int* __restrict__ dst,
                       int* __restrict__ cursor, int* __restrict__ elist) {
    int e = blockIdx.x * 256 + threadIdx.x;
    if (e < NE) {
        int p = atomicAdd(&cursor[dst[e]], 1);
        elist[p] = src[e];
    }
}

// ---------------- GCN layer 1 ----------------
// t1 = feat @ gc1_W   [NN,128] @ [128,100]
__global__ __launch_bounds__(256, 2) void k_gemm1(const float* __restrict__ feat,
                                                  const float* __restrict__ W,
                                                  float* __restrict__ t1) {
    __shared__ float sWT[C1 * DIN];      // 51.2 KB  sWT[col*128 + (k ^ ((col&7)<<2))]
    __shared__ float sf[32][DIN + 4];    // 16.9 KB  padded rows
    const int tid = threadIdx.x;
    for (int idx = tid; idx < DIN * C1; idx += 256) {
        int k = idx / C1, col = idx % C1;
        sWT[col * DIN + (k ^ ((col & 7) << 2))] = W[idx];
    }
    const int j = tid & 63;              // active j<50: cols j, j+50
    const int rg = tid >> 6;             // 0..3
    const bool act = j < 50;
    const int c0 = j, c1 = j + 50;
    const int swz0 = (c0 & 7) << 2, swz1 = (c1 & 7) << 2;

    for (int n0 = blockIdx.x * 32; n0 < NN; n0 += gridDim.x * 32) {
        __syncthreads();
        {   // stage 32 feat rows, 16 floats per thread
            int r = tid >> 3, so = (tid & 7) * 16;
            int n = n0 + r;
            float4* dstp = (float4*)&sf[r][so];
            if (n < NN) {
                const float4* srcp = (const float4*)(feat + (size_t)n * DIN + so);
                dstp[0] = srcp[0]; dstp[1] = srcp[1]; dstp[2] = srcp[2]; dstp[3] = srcp[3];
            } else {
                float4 z = {0.f, 0.f, 0.f, 0.f};
                dstp[0] = z; dstp[1] = z; dstp[2] = z; dstp[3] = z;
            }
        }
        __syncthreads();
        if (act) {
            float acc0[8], acc1[8];
            #pragma unroll
            for (int r = 0; r < 8; ++r) { acc0[r] = 0.f; acc1[r] = 0.f; }
            #pragma unroll 4
            for (int kc = 0; kc < DIN; kc += 4) {
                float4 w0 = *(const float4*)&sWT[c0 * DIN + (kc ^ swz0)];
                float4 w1 = *(const float4*)&sWT[c1 * DIN + (kc ^ swz1)];
                #pragma unroll
                for (int r = 0; r < 8; ++r) {
                    float4 a = *(const float4*)&sf[rg * 8 + r][kc];
                    acc0[r] += a.x * w0.x; acc0[r] += a.y * w0.y;
                    acc0[r] += a.z * w0.z; acc0[r] += a.w * w0.w;
                    acc1[r] += a.x * w1.x; acc1[r] += a.y * w1.y;
                    acc1[r] += a.z * w1.z; acc1[r] += a.w * w1.w;
                }
            }
            #pragma unroll
            for (int r = 0; r < 8; ++r) {
                int n = n0 + rg * 8 + r;
                if (n < NN) {
                    t1[(size_t)n * C1 + c0] = acc0[r];
                    t1[(size_t)n * C1 + c1] = acc1[r];
                }
            }
        }
    }
}

// h1 = relu(csr_mean(t1) + b)
__global__ void k_agg1(const float* __restrict__ t1, const int* __restrict__ row_ptr,
                       const int* __restrict__ elist, const int* __restrict__ cnt,
                       const float* __restrict__ bias, float* __restrict__ h1) {
    const int n = blockIdx.x;
    const int c = threadIdx.x;          // 128 threads, c<100 active
    if (c >= C1) return;
    int e0 = row_ptr[n], e1 = row_ptr[n + 1];
    float acc = 0.f;
    int e = e0;
    for (; e + 3 < e1; e += 4) {
        int s0 = elist[e], s1 = elist[e + 1], s2 = elist[e + 2], s3 = elist[e + 3];
        acc += t1[s0 * C1 + c];
        acc += t1[s1 * C1 + c];
        acc += t1[s2 * C1 + c];
        acc += t1[s3 * C1 + c];
    }
    for (; e < e1; ++e) acc += t1[elist[e] * C1 + c];
    float d = (float)cnt[n]; d = d > 1.f ? d : 1.f;
    float v = acc / d + bias[c];
    h1[n * C1 + c] = v > 0.f ? v : 0.f;
}

// ---------------- GCN layer 2 ----------------
// t2 = h1 @ gc2_W   [NN,100] @ [100,20]
__global__ void k_gemm2(const float* __restrict__ h1, const float* __restrict__ W,
                        float* __restrict__ t2) {
    __shared__ float sW[C1 * C2];       // 8000 B
    __shared__ float sr[16][C1];        // 6400 B
    for (int idx = threadIdx.x; idx < C1 * C2; idx += 320) sW[idx] = W[idx];
    int ln = threadIdx.x / C2, j = threadIdx.x % C2;   // ln<16
    int n0 = blockIdx.x * 16;
    __syncthreads();
    for (int idx = threadIdx.x; idx < 16 * C1; idx += 320) {
        int r = idx / C1, k = idx % C1;
        int n = n0 + r;
        sr[r][k] = (n < NN) ? h1[n * C1 + k] : 0.f;
    }
    __syncthreads();
    int n = n0 + ln;
    if (n < NN && ln < 16) {
        float acc = 0.f;
        #pragma unroll 4
        for (int k = 0; k < C1; ++k) acc += sr[ln][k] * sW[k * C2 + j];
        t2[n * C2 + j] = acc;
    }
}

__global__ void k_agg2(const float* __restrict__ t2, const int* __restrict__ row_ptr,
                       const int* __restrict__ elist, const int* __restrict__ cnt,
                       const float* __restrict__ bias, float* __restrict__ h2) {
    int ln = threadIdx.x / C2, c = threadIdx.x % C2;
    if (ln >= 12) return;
    int n = blockIdx.x * 12 + ln;
    if (n >= NN) return;
    int e0 = row_ptr[n], e1 = row_ptr[n + 1];
    float acc = 0.f;
    int e = e0;
    for (; e + 1 < e1; e += 2) {
        int s0 = elist[e], s1 = elist[e + 1];
        acc += t2[s0 * C2 + c];
        acc += t2[s1 * C2 + c];
    }
    for (; e < e1; ++e) acc += t2[elist[e] * C2 + c];
    float d = (float)cnt[n]; d = d > 1.f ? d : 1.f;
    float v = acc / d + bias[c];
    h2[n * C2 + c] = v > 0.f ? v : 0.f;
}

// ---------------- graph mean pool ----------------
__global__ void k_pool(const float* __restrict__ h2, const int* __restrict__ gid,
                       float* __restrict__ hgs) {
    int idx = blockIdx.x * 256 + threadIdx.x;
    if (idx < NN * C2) {
        int n = idx / C2, c = idx % C2;
        atomicAdd(&hgs[gid[n] * C2 + c], h2[idx]);
    }
}

__global__ void k_hgdiv(const float* __restrict__ hgs, const int* __restrict__ gcnt,
                        float* __restrict__ hg) {
    int idx = blockIdx.x * 256 + threadIdx.x;
    if (idx < NB * C2) {
        float d = (float)gcnt[idx / C2]; d = d > 1.f ? d : 1.f;
        hg[idx] = hgs[idx] / d;
    }
}

// ---------------- attention head ----------------
__global__ void k_head(const float* __restrict__ hg, const float* __restrict__ desc2d,
                       const float* __restrict__ pgW, const float* __restrict__ pgb,
                       const float* __restrict__ p2W, const float* __restrict__ p2b,
                       const float* __restrict__ W2, float* __restrict__ a_out) {
    __shared__ float shg[C2];
    __shared__ float sg[DHH];
    int b = blockIdx.x, j = threadIdx.x;   // 64 threads
    if (j < C2) shg[j] = hg[b * C2 + j];
    __syncthreads();
    float hgj = pgb[j];
    #pragma unroll
    for (int k = 0; k < C2; ++k) hgj += shg[k] * pgW[k * DHH + j];
    float hdj = p2b[j];
    #pragma unroll 4
    for (int k = 0; k < DD2; ++k) hdj += desc2d[b * DD2 + k] * p2W[k * DHH + j];
    sg[j] = hgj;
    __syncthreads();
    float tj = 0.f;
    #pragma unroll 4
    for (int k = 0; k < DHH; ++k) tj += sg[k] * W2[k * DHH + j];
    float v = tj * hdj;
    #pragma unroll
    for (int off = 32; off; off >>= 1) v += __shfl_xor(v, off, 64);
    if (j == 0) a_out[b] = 1.f / (1.f + expf(-v));
}

// ---------------- fc1 via rank-1 factorization ----------------
// d1ext[b][k] = a[b]*desc2d[b][k] (k<200), 1 (k==200), 0 (pad)
__global__ void k_prep(const float* __restrict__ desc2d, const float* __restrict__ a,
                       float* __restrict__ d1ext) {
    int idx = blockIdx.x * 256 + threadIdx.x;
    if (idx < NB * KDP) {
        int b = idx / KDP, k = idx % KDP;
        float v = (k < DD2) ? a[b] * desc2d[b * DD2 + k] : (k == DD2 ? 1.f : 0.f);
        d1ext[idx] = v;
    }
}

// U[b][i*128+j] = sum_k d1ext[b][k] * W1[(i*201+k)*128+j]
// grid (16, 21): x = bt*2+half; block 256 = 32 cols x 8 rowgroups; acc 8 rows x 2 cols
__global__ __launch_bounds__(256, 2) void k_fc1(const float* __restrict__ d1ext,
                                                const float* __restrict__ W1,
                                                float* __restrict__ U) {
    __shared__ float S[64][KDP];         // 52.2 KB
    const int i = blockIdx.y;            // 0..20
    const int bt = blockIdx.x >> 1;      // 0..7 (64-row tile)
    const int half = blockIdx.x & 1;     // col half (64 cols)
    const int tid = threadIdx.x;
    const int c = tid & 31;
    const int rg = tid >> 5;             // 0..7

    {   // stage 64 d1ext rows
        const float4* srcp = (const float4*)(d1ext + (size_t)bt * 64 * KDP);
        float4* dstp = (float4*)&S[0][0];
        for (int idx = tid; idx < 64 * (KDP / 4); idx += 256) dstp[idx] = srcp[idx];
    }
    __syncthreads();

    float acc[8][2];
    #pragma unroll
    for (int r = 0; r < 8; ++r) { acc[r][0] = 0.f; acc[r][1] = 0.f; }

    const float* Wb = W1 + (size_t)i * (KD * HH1) + half * 64 + c;
    for (int k = 0; k < 200; k += 4) {
        const float* Wk = Wb + (size_t)k * HH1;
        float w0[2], w1[2], w2[2], w3[2];
        #pragma unroll
        for (int m = 0; m < 2; ++m) {
            w0[m] = Wk[32 * m];
            w1[m] = Wk[HH1 + 32 * m];
            w2[m] = Wk[2 * HH1 + 32 * m];
            w3[m] = Wk[3 * HH1 + 32 * m];
        }
        #pragma unroll
        for (int r = 0; r < 8; ++r) {
            float4 a4 = *(const float4*)&S[rg * 8 + r][k];
            #pragma unroll
            for (int m = 0; m < 2; ++m)
                acc[r][m] += a4.x * w0[m] + a4.y * w1[m] + a4.z * w2[m] + a4.w * w3[m];
        }
    }
    {   // k = 200 (the "+1" column of d1)
        const float* Wk = Wb + (size_t)200 * HH1;
        float wl0 = Wk[0], wl1 = Wk[32];
        #pragma unroll
        for (int r = 0; r < 8; ++r) {
            float av = S[rg * 8 + r][200];
            acc[r][0] += av * wl0;
            acc[r][1] += av * wl1;
        }
    }
    #pragma unroll
    for (int r = 0; r < 8; ++r) {
        int b = bt * 64 + rg * 8 + r;
        float* Ur = U + (size_t)b * NU + i * HH1 + half * 64 + c;
        Ur[0] = acc[r][0];
        Ur[32] = acc[r][1];
    }
}

// o1[b][j] = U[b][20*128+j] + sum_{i<20} hg[b][i] * U[b][i*128+j]
__global__ void k_fc1b(const float* __restrict__ U, const float* __restrict__ hg,
                       float* __restrict__ o1) {
    int idx = blockIdx.x * 256 + threadIdx.x;   // 65536
    int b = idx >> 7, j = idx & 127;
    const float* Ub = U + (size_t)b * NU + j;
    const float* hgb = hg + b * C2;
    float acc = Ub[20 * HH1];
    #pragma unroll
    for (int i = 0; i < 20; ++i) acc += hgb[i] * Ub[i * HH1];
    o1[idx] = acc;
}

// ---------------- batch-norm stats (mean + rstd per column), row-parallel ----------------
__global__ void k_bnstats(const float* __restrict__ x, float* __restrict__ stats,
                          int ncols, int nrows) {
    __shared__ float sh[1024], sh2[1024];
    const int tid = threadIdx.x;
    const int j = tid % ncols;
    const int r = tid / ncols;
    const int R = 1024 / ncols;
    float s = 0.f, s2 = 0.f;
    for (int b = r; b < nrows; b += R) {
        float v = x[b * ncols + j];
        s += v; s2 += v * v;
    }
    sh[tid] = s; sh2[tid] = s2;
    __syncthreads();
    if (r == 0) {
        for (int q = 1; q < R; ++q) { s += sh[q * ncols + j]; s2 += sh2[q * ncols + j]; }
        float mu = s / nrows;
        float var = s2 / nrows - mu * mu;
        stats[j] = mu;
        stats[ncols + j] = rsqrtf(var + 1e-5f);
    }
}

// ---------------- fc2 (bn1 + relu fused in; fc2 bias dropped) ----------------
__global__ void k_fc2(const float* __restrict__ o1, const float* __restrict__ st1,
                      const float* __restrict__ g, const float* __restrict__ beta,
                      const float* __restrict__ W, float* __restrict__ o2) {
    __shared__ float r[HH1];
    __shared__ float part[4][HH2];
    int b = blockIdx.x;
    int tid = threadIdx.x;   // 128
    float v = o1[b * HH1 + tid];
    float nv = (v - st1[tid]) * st1[HH1 + tid] * g[tid] + beta[tid];
    r[tid] = fmaxf(nv, 0.f);
    __syncthreads();
    int m = tid & 31, p = tid >> 5;
    float acc = 0.f;
    #pragma unroll 4
    for (int j = p * 32; j < p * 32 + 32; ++j) acc += r[j] * W[j * HH2 + m];
    part[p][m] = acc;
    __syncthreads();
    if (tid < HH2) o2[b * HH2 + tid] = part[0][tid] + part[1][tid] + part[2][tid] + part[3][tid];
}

// ---------------- bn2 + relu + fc3 ----------------
__global__ void k_final(const float* __restrict__ o2, const float* __restrict__ st2,
                        const float* __restrict__ g, const float* __restrict__ beta,
                        const float* __restrict__ W3, const float* __restrict__ b3,
                        float* __restrict__ out) {
    int b = threadIdx.x;    // 512
    if (b < NB) {
        float acc = b3[0];
        #pragma unroll 4
        for (int m = 0; m < HH2; ++m) {
            float v = o2[b * HH2 + m];
            float nv = (v - st2[m]) * st2[HH2 + m] * g[m] + beta[m];
            acc += fmaxf(nv, 0.f) * W3[m];
        }
        out[b] = acc;
    }
}

extern "C" void kernel_launch(void* const* d_in, const int* in_sizes, int n_in,
                              void* d_out, int out_size, void* d_ws, size_t ws_size,
                              hipStream_t stream) {
    const float* feat   = (const float*)d_in[0];
    const float* desc2d = (const float*)d_in[1];
    const float* gc1W = (const float*)d_in[3];
    const float* gc1b = (const float*)d_in[4];
    const float* gc2W = (const float*)d_in[5];
    const float* gc2b = (const float*)d_in[6];
    const float* pgW  = (const float*)d_in[7];
    const float* pgb  = (const float*)d_in[8];
    const float* p2W  = (const float*)d_in[9];
    const float* p2b  = (const float*)d_in[10];
    const float* W2   = (const float*)d_in[11];
    const float* fc1W = (const float*)d_in[12];
    const float* fc2W = (const float*)d_in[14];
    const float* fc3W = (const float*)d_in[16];
    const float* fc3b = (const float*)d_in[17];
    const float* bn1g = (const float*)d_in[18];
    const float* bn1b = (const float*)d_in[19];
    const float* bn2g = (const float*)d_in[20];
    const float* bn2b = (const float*)d_in[21];
    const int* src = (const int*)d_in[22];
    const int* dst = (const int*)d_in[23];
    const int* gid = (const int*)d_in[24];
    float* out = (float*)d_out;

    char* ws = (char*)d_ws;
    size_t off = 0;
    auto alloc = [&](size_t nb) {
        void* p = ws + off;
        off = (off + nb + 255) & ~(size_t)255;
        return p;
    };
    float* t1    = (float*)alloc((size_t)NN * C1 * 4);
    float* h1    = (float*)alloc((size_t)NN * C1 * 4);
    int* cnt_in  = (int*)alloc((size_t)NN * 4);
    int* row_ptr = (int*)alloc((size_t)(NN + 1) * 4);
    int* cursor  = (int*)alloc((size_t)NN * 4);
    int* elist   = (int*)alloc((size_t)NE * 4);
    int* gcnt    = (int*)alloc((size_t)NB * 4);
    float* hgs   = (float*)alloc((size_t)NB * C2 * 4);
    float* hg    = (float*)alloc((size_t)NB * C2 * 4);
    float* avec  = (float*)alloc((size_t)NB * 4);
    float* o1    = (float*)alloc((size_t)NB * HH1 * 4);
    float* st1   = (float*)alloc(2 * HH1 * 4);
    float* o2    = (float*)alloc((size_t)NB * HH2 * 4);
    float* st2   = (float*)alloc(2 * HH2 * 4);
    float* t2 = t1;   // t1 dead after h1 computed
    float* h2 = h1;   // h1 dead after t2 computed
    // fc1 scratch aliases t1 (t1/t2 dead after k_agg2; fc1 runs after k_pool)
    float* U     = t1;                                  // 512*2688*4 = 5.5 MB
    float* d1ext = t1 + (size_t)NB * NU;                // 512*204*4 = 418 KB

    hipMemsetAsync(cnt_in, 0, (size_t)NN * 4, stream);
    hipMemsetAsync(gcnt, 0, (size_t)NB * 4, stream);
    hipMemsetAsync(hgs, 0, (size_t)NB * C2 * 4, stream);

    k_count<<<(NE + 255) / 256, 256, 0, stream>>>(dst, cnt_in);
    k_gcount<<<(NN + 255) / 256, 256, 0, stream>>>(gid, gcnt);
    k_scan<<<1, 1024, 0, stream>>>(cnt_in, row_ptr, cursor, NN);
    k_fill<<<(NE + 255) / 256, 256, 0, stream>>>(src, dst, cursor, elist);

    k_gemm1<<<512, 256, 0, stream>>>(feat, gc1W, t1);
    k_agg1<<<NN, 128, 0, stream>>>(t1, row_ptr, elist, cnt_in, gc1b, h1);

    k_gemm2<<<(NN + 15) / 16, 320, 0, stream>>>(h1, gc2W, t2);
    k_agg2<<<(NN + 11) / 12, 256, 0, stream>>>(t2, row_ptr, elist, cnt_in, gc2b, h2);

    k_pool<<<(NN * C2 + 255) / 256, 256, 0, stream>>>(h2, gid, hgs);
    k_hgdiv<<<(NB * C2 + 255) / 256, 256, 0, stream>>>(hgs, gcnt, hg);

    k_head<<<NB, 64, 0, stream>>>(hg, desc2d, pgW, pgb, p2W, p2b, W2, avec);

    k_prep<<<(NB * KDP + 255) / 256, 256, 0, stream>>>(desc2d, avec, d1ext);
    dim3 g1(16, 21);
    k_fc1<<<g1, 256, 0, stream>>>(d1ext, fc1W, U);
    k_fc1b<<<NB * HH1 / 256, 256, 0, stream>>>(U, hg, o1);

    k_bnstats<<<1, 1024, 0, stream>>>(o1, st1, HH1, NB);
    k_fc2<<<NB, 128, 0, stream>>>(o1, st1, bn1g, bn1b, fc2W, o2);
    k_bnstats<<<1, 1024, 0, stream>>>(o2, st2, HH2, NB);
    k_final<<<1, 512, 0, stream>>>(o2, st2, bn2g, bn2b, fc3W, fc3b, out);
}

// Round 5
// 374.027 us; speedup vs baseline: 1.9398x; 1.1475x over previous
//
#include <hip/hip_runtime.h>

#define NN 50000
#define NE 800000
#define NB 512
#define DIN 128
#define DD2 200
#define C1 100
#define C2 20
#define DHH 64
#define HH1 128
#define HH2 32
#define KD 201      // fusion inner dim per i (200 + 1)
#define KDP 204     // padded row stride for d1ext
#define NU 2688     // 21 * 128
#define SCB 196     // scan blocks: ceil(50000/256)

// ---------------- CSR build ----------------
__global__ void k_count(const int* __restrict__ dst, int* __restrict__ cnt) {
    int e = blockIdx.x * 256 + threadIdx.x;
    if (e < NE) atomicAdd(&cnt[dst[e]], 1);
}

__global__ void k_gcount(const int* __restrict__ gid, int* __restrict__ gcnt) {
    int n = blockIdx.x * 256 + threadIdx.x;
    if (n < NN) atomicAdd(&gcnt[gid[n]], 1);
}

// -------- 3-phase device-wide exclusive scan of cnt[NN] --------
// phase 1: per-block exclusive scan -> row_ptr (local), block totals -> bsum
__global__ void k_scan1(const int* __restrict__ cnt, int* __restrict__ row_ptr,
                        int* __restrict__ bsum) {
    __shared__ int wsum[4];
    const int tid = threadIdx.x;          // 256
    const int lane = tid & 63, wid = tid >> 6;
    int i = blockIdx.x * 256 + tid;
    int v = (i < NN) ? cnt[i] : 0;
    int x = v;
    #pragma unroll
    for (int d = 1; d < 64; d <<= 1) {
        int t = __shfl_up(x, d, 64);
        if (lane >= d) x += t;
    }
    if (lane == 63) wsum[wid] = x;
    __syncthreads();
    int wpref = 0;
    #pragma unroll
    for (int w = 0; w < 4; ++w) if (w < wid) wpref += wsum[w];
    if (i < NN) row_ptr[i] = wpref + x - v;
    if (tid == 255) bsum[blockIdx.x] = wpref + x;
}

// phase 2: scan the SCB block totals (one block, 256 threads) -> exclusive offsets
__global__ void k_scan2(int* __restrict__ bsum, int* __restrict__ row_ptr) {
    __shared__ int wsum[4];
    const int tid = threadIdx.x;
    const int lane = tid & 63, wid = tid >> 6;
    int v = (tid < SCB) ? bsum[tid] : 0;
    int x = v;
    #pragma unroll
    for (int d = 1; d < 64; d <<= 1) {
        int t = __shfl_up(x, d, 64);
        if (lane >= d) x += t;
    }
    if (lane == 63) wsum[wid] = x;
    __syncthreads();
    int wpref = 0;
    #pragma unroll
    for (int w = 0; w < 4; ++w) if (w < wid) wpref += wsum[w];
    if (tid < SCB) bsum[tid] = wpref + x - v;   // exclusive offset
    if (tid == 255) row_ptr[NN] = wpref + x;    // grand total (= NE)
}

// phase 3: add block offsets, init cursor
__global__ void k_scan3(int* __restrict__ row_ptr, const int* __restrict__ bsum,
                        int* __restrict__ cursor) {
    int i = blockIdx.x * 256 + threadIdx.x;
    if (i < NN) {
        int e = row_ptr[i] + bsum[blockIdx.x];
        row_ptr[i] = e;
        cursor[i] = e;
    }
}

__global__ void k_fill(const int* __restrict__ src, const int* __restrict__ dst,
                       int* __restrict__ cursor, int* __restrict__ elist) {
    int e = blockIdx.x * 256 + threadIdx.x;
    if (e < NE) {
        int p = atomicAdd(&cursor[dst[e]], 1);
        elist[p] = src[e];
    }
}

// ---------------- GCN layer 1 ----------------
// t1 = feat @ gc1_W   [NN,128] @ [128,100]
__global__ __launch_bounds__(256, 2) void k_gemm1(const float* __restrict__ feat,
                                                  const float* __restrict__ W,
                                                  float* __restrict__ t1) {
    __shared__ float sWT[C1 * DIN];      // 51.2 KB  sWT[col*128 + (k ^ ((col&7)<<2))]
    __shared__ float sf[32][DIN + 4];    // 16.9 KB  padded rows
    const int tid = threadIdx.x;
    for (int idx = tid; idx < DIN * C1; idx += 256) {
        int k = idx / C1, col = idx % C1;
        sWT[col * DIN + (k ^ ((col & 7) << 2))] = W[idx];
    }
    const int j = tid & 63;              // active j<50: cols j, j+50
    const int rg = tid >> 6;             // 0..3
    const bool act = j < 50;
    const int c0 = j, c1 = j + 50;
    const int swz0 = (c0 & 7) << 2, swz1 = (c1 & 7) << 2;

    for (int n0 = blockIdx.x * 32; n0 < NN; n0 += gridDim.x * 32) {
        __syncthreads();
        {   // stage 32 feat rows, 16 floats per thread
            int r = tid >> 3, so = (tid & 7) * 16;
            int n = n0 + r;
            float4* dstp = (float4*)&sf[r][so];
            if (n < NN) {
                const float4* srcp = (const float4*)(feat + (size_t)n * DIN + so);
                dstp[0] = srcp[0]; dstp[1] = srcp[1]; dstp[2] = srcp[2]; dstp[3] = srcp[3];
            } else {
                float4 z = {0.f, 0.f, 0.f, 0.f};
                dstp[0] = z; dstp[1] = z; dstp[2] = z; dstp[3] = z;
            }
        }
        __syncthreads();
        if (act) {
            float acc0[8], acc1[8];
            #pragma unroll
            for (int r = 0; r < 8; ++r) { acc0[r] = 0.f; acc1[r] = 0.f; }
            #pragma unroll 4
            for (int kc = 0; kc < DIN; kc += 4) {
                float4 w0 = *(const float4*)&sWT[c0 * DIN + (kc ^ swz0)];
                float4 w1 = *(const float4*)&sWT[c1 * DIN + (kc ^ swz1)];
                #pragma unroll
                for (int r = 0; r < 8; ++r) {
                    float4 a = *(const float4*)&sf[rg * 8 + r][kc];
                    acc0[r] += a.x * w0.x; acc0[r] += a.y * w0.y;
                    acc0[r] += a.z * w0.z; acc0[r] += a.w * w0.w;
                    acc1[r] += a.x * w1.x; acc1[r] += a.y * w1.y;
                    acc1[r] += a.z * w1.z; acc1[r] += a.w * w1.w;
                }
            }
            #pragma unroll
            for (int r = 0; r < 8; ++r) {
                int n = n0 + rg * 8 + r;
                if (n < NN) {
                    t1[(size_t)n * C1 + c0] = acc0[r];
                    t1[(size_t)n * C1 + c1] = acc1[r];
                }
            }
        }
    }
}

// h1 = relu(csr_mean(t1) + b)
__global__ void k_agg1(const float* __restrict__ t1, const int* __restrict__ row_ptr,
                       const int* __restrict__ elist, const int* __restrict__ cnt,
                       const float* __restrict__ bias, float* __restrict__ h1) {
    const int n = blockIdx.x;
    const int c = threadIdx.x;          // 128 threads, c<100 active
    if (c >= C1) return;
    int e0 = row_ptr[n], e1 = row_ptr[n + 1];
    float acc = 0.f;
    int e = e0;
    for (; e + 3 < e1; e += 4) {
        int s0 = elist[e], s1 = elist[e + 1], s2 = elist[e + 2], s3 = elist[e + 3];
        acc += t1[s0 * C1 + c];
        acc += t1[s1 * C1 + c];
        acc += t1[s2 * C1 + c];
        acc += t1[s3 * C1 + c];
    }
    for (; e < e1; ++e) acc += t1[elist[e] * C1 + c];
    float d = (float)cnt[n]; d = d > 1.f ? d : 1.f;
    float v = acc / d + bias[c];
    h1[n * C1 + c] = v > 0.f ? v : 0.f;
}

// ---------------- GCN layer 2 ----------------
// t2 = h1 @ gc2_W   [NN,100] @ [100,20]
__global__ void k_gemm2(const float* __restrict__ h1, const float* __restrict__ W,
                        float* __restrict__ t2) {
    __shared__ float sW[C1 * C2];       // 8000 B
    __shared__ float sr[16][C1];        // 6400 B
    for (int idx = threadIdx.x; idx < C1 * C2; idx += 320) sW[idx] = W[idx];
    int ln = threadIdx.x / C2, j = threadIdx.x % C2;   // ln<16
    int n0 = blockIdx.x * 16;
    __syncthreads();
    for (int idx = threadIdx.x; idx < 16 * C1; idx += 320) {
        int r = idx / C1, k = idx % C1;
        int n = n0 + r;
        sr[r][k] = (n < NN) ? h1[n * C1 + k] : 0.f;
    }
    __syncthreads();
    int n = n0 + ln;
    if (n < NN && ln < 16) {
        float acc = 0.f;
        #pragma unroll 4
        for (int k = 0; k < C1; ++k) acc += sr[ln][k] * sW[k * C2 + j];
        t2[n * C2 + j] = acc;
    }
}

__global__ void k_agg2(const float* __restrict__ t2, const int* __restrict__ row_ptr,
                       const int* __restrict__ elist, const int* __restrict__ cnt,
                       const float* __restrict__ bias, float* __restrict__ h2) {
    int ln = threadIdx.x / C2, c = threadIdx.x % C2;
    if (ln >= 12) return;
    int n = blockIdx.x * 12 + ln;
    if (n >= NN) return;
    int e0 = row_ptr[n], e1 = row_ptr[n + 1];
    float acc = 0.f;
    int e = e0;
    for (; e + 1 < e1; e += 2) {
        int s0 = elist[e], s1 = elist[e + 1];
        acc += t2[s0 * C2 + c];
        acc += t2[s1 * C2 + c];
    }
    for (; e < e1; ++e) acc += t2[elist[e] * C2 + c];
    float d = (float)cnt[n]; d = d > 1.f ? d : 1.f;
    float v = acc / d + bias[c];
    h2[n * C2 + c] = v > 0.f ? v : 0.f;
}

// ---------------- graph mean pool ----------------
__global__ void k_pool(const float* __restrict__ h2, const int* __restrict__ gid,
                       float* __restrict__ hgs) {
    int idx = blockIdx.x * 256 + threadIdx.x;
    if (idx < NN * C2) {
        int n = idx / C2, c = idx % C2;
        atomicAdd(&hgs[gid[n] * C2 + c], h2[idx]);
    }
}

__global__ void k_hgdiv(const float* __restrict__ hgs, const int* __restrict__ gcnt,
                        float* __restrict__ hg) {
    int idx = blockIdx.x * 256 + threadIdx.x;
    if (idx < NB * C2) {
        float d = (float)gcnt[idx / C2]; d = d > 1.f ? d : 1.f;
        hg[idx] = hgs[idx] / d;
    }
}

// ---------------- attention head ----------------
__global__ void k_head(const float* __restrict__ hg, const float* __restrict__ desc2d,
                       const float* __restrict__ pgW, const float* __restrict__ pgb,
                       const float* __restrict__ p2W, const float* __restrict__ p2b,
                       const float* __restrict__ W2, float* __restrict__ a_out) {
    __shared__ float shg[C2];
    __shared__ float sg[DHH];
    int b = blockIdx.x, j = threadIdx.x;   // 64 threads
    if (j < C2) shg[j] = hg[b * C2 + j];
    __syncthreads();
    float hgj = pgb[j];
    #pragma unroll
    for (int k = 0; k < C2; ++k) hgj += shg[k] * pgW[k * DHH + j];
    float hdj = p2b[j];
    #pragma unroll 4
    for (int k = 0; k < DD2; ++k) hdj += desc2d[b * DD2 + k] * p2W[k * DHH + j];
    sg[j] = hgj;
    __syncthreads();
    float tj = 0.f;
    #pragma unroll 4
    for (int k = 0; k < DHH; ++k) tj += sg[k] * W2[k * DHH + j];
    float v = tj * hdj;
    #pragma unroll
    for (int off = 32; off; off >>= 1) v += __shfl_xor(v, off, 64);
    if (j == 0) a_out[b] = 1.f / (1.f + expf(-v));
}

// ---------------- fc1 via rank-1 factorization ----------------
__global__ void k_prep(const float* __restrict__ desc2d, const float* __restrict__ a,
                       float* __restrict__ d1ext) {
    int idx = blockIdx.x * 256 + threadIdx.x;
    if (idx < NB * KDP) {
        int b = idx / KDP, k = idx % KDP;
        float v = (k < DD2) ? a[b] * desc2d[b * DD2 + k] : (k == DD2 ? 1.f : 0.f);
        d1ext[idx] = v;
    }
}

// U[b][i*128+j] = sum_k d1ext[b][k] * W1[(i*201+k)*128+j]
__global__ __launch_bounds__(256, 2) void k_fc1(const float* __restrict__ d1ext,
                                                const float* __restrict__ W1,
                                                float* __restrict__ U) {
    __shared__ float S[64][KDP];         // 52.2 KB
    const int i = blockIdx.y;            // 0..20
    const int bt = blockIdx.x >> 1;      // 0..7 (64-row tile)
    const int half = blockIdx.x & 1;     // col half (64 cols)
    const int tid = threadIdx.x;
    const int c = tid & 31;
    const int rg = tid >> 5;             // 0..7

    {   // stage 64 d1ext rows
        const float4* srcp = (const float4*)(d1ext + (size_t)bt * 64 * KDP);
        float4* dstp = (float4*)&S[0][0];
        for (int idx = tid; idx < 64 * (KDP / 4); idx += 256) dstp[idx] = srcp[idx];
    }
    __syncthreads();

    float acc[8][2];
    #pragma unroll
    for (int r = 0; r < 8; ++r) { acc[r][0] = 0.f; acc[r][1] = 0.f; }

    const float* Wb = W1 + (size_t)i * (KD * HH1) + half * 64 + c;
    for (int k = 0; k < 200; k += 4) {
        const float* Wk = Wb + (size_t)k * HH1;
        float w0[2], w1[2], w2[2], w3[2];
        #pragma unroll
        for (int m = 0; m < 2; ++m) {
            w0[m] = Wk[32 * m];
            w1[m] = Wk[HH1 + 32 * m];
            w2[m] = Wk[2 * HH1 + 32 * m];
            w3[m] = Wk[3 * HH1 + 32 * m];
        }
        #pragma unroll
        for (int r = 0; r < 8; ++r) {
            float4 a4 = *(const float4*)&S[rg * 8 + r][k];
            #pragma unroll
            for (int m = 0; m < 2; ++m)
                acc[r][m] += a4.x * w0[m] + a4.y * w1[m] + a4.z * w2[m] + a4.w * w3[m];
        }
    }
    {   // k = 200 (the "+1" column of d1)
        const float* Wk = Wb + (size_t)200 * HH1;
        float wl0 = Wk[0], wl1 = Wk[32];
        #pragma unroll
        for (int r = 0; r < 8; ++r) {
            float av = S[rg * 8 + r][200];
            acc[r][0] += av * wl0;
            acc[r][1] += av * wl1;
        }
    }
    #pragma unroll
    for (int r = 0; r < 8; ++r) {
        int b = bt * 64 + rg * 8 + r;
        float* Ur = U + (size_t)b * NU + i * HH1 + half * 64 + c;
        Ur[0] = acc[r][0];
        Ur[32] = acc[r][1];
    }
}

// o1[b][j] = U[b][20*128+j] + sum_{i<20} hg[b][i] * U[b][i*128+j]
__global__ void k_fc1b(const float* __restrict__ U, const float* __restrict__ hg,
                       float* __restrict__ o1) {
    int idx = blockIdx.x * 256 + threadIdx.x;   // 65536
    int b = idx >> 7, j = idx & 127;
    const float* Ub = U + (size_t)b * NU + j;
    const float* hgb = hg + b * C2;
    float acc = Ub[20 * HH1];
    #pragma unroll
    for (int i = 0; i < 20; ++i) acc += hgb[i] * Ub[i * HH1];
    o1[idx] = acc;
}

// ---------------- batch-norm stats (mean + rstd per column), row-parallel ----------------
__global__ void k_bnstats(const float* __restrict__ x, float* __restrict__ stats,
                          int ncols, int nrows) {
    __shared__ float sh[1024], sh2[1024];
    const int tid = threadIdx.x;
    const int j = tid % ncols;
    const int r = tid / ncols;
    const int R = 1024 / ncols;
    float s = 0.f, s2 = 0.f;
    for (int b = r; b < nrows; b += R) {
        float v = x[b * ncols + j];
        s += v; s2 += v * v;
    }
    sh[tid] = s; sh2[tid] = s2;
    __syncthreads();
    if (r == 0) {
        for (int q = 1; q < R; ++q) { s += sh[q * ncols + j]; s2 += sh2[q * ncols + j]; }
        float mu = s / nrows;
        float var = s2 / nrows - mu * mu;
        stats[j] = mu;
        stats[ncols + j] = rsqrtf(var + 1e-5f);
    }
}

// ---------------- fc2 (bn1 + relu fused in; fc2 bias dropped) ----------------
__global__ void k_fc2(const float* __restrict__ o1, const float* __restrict__ st1,
                      const float* __restrict__ g, const float* __restrict__ beta,
                      const float* __restrict__ W, float* __restrict__ o2) {
    __shared__ float r[HH1];
    __shared__ float part[4][HH2];
    int b = blockIdx.x;
    int tid = threadIdx.x;   // 128
    float v = o1[b * HH1 + tid];
    float nv = (v - st1[tid]) * st1[HH1 + tid] * g[tid] + beta[tid];
    r[tid] = fmaxf(nv, 0.f);
    __syncthreads();
    int m = tid & 31, p = tid >> 5;
    float acc = 0.f;
    #pragma unroll 4
    for (int j = p * 32; j < p * 32 + 32; ++j) acc += r[j] * W[j * HH2 + m];
    part[p][m] = acc;
    __syncthreads();
    if (tid < HH2) o2[b * HH2 + tid] = part[0][tid] + part[1][tid] + part[2][tid] + part[3][tid];
}

// ---------------- bn2 + relu + fc3 ----------------
__global__ void k_final(const float* __restrict__ o2, const float* __restrict__ st2,
                        const float* __restrict__ g, const float* __restrict__ beta,
                        const float* __restrict__ W3, const float* __restrict__ b3,
                        float* __restrict__ out) {
    int b = threadIdx.x;    // 512
    if (b < NB) {
        float acc = b3[0];
        #pragma unroll 4
        for (int m = 0; m < HH2; ++m) {
            float v = o2[b * HH2 + m];
            float nv = (v - st2[m]) * st2[HH2 + m] * g[m] + beta[m];
            acc += fmaxf(nv, 0.f) * W3[m];
        }
        out[b] = acc;
    }
}

extern "C" void kernel_launch(void* const* d_in, const int* in_sizes, int n_in,
                              void* d_out, int out_size, void* d_ws, size_t ws_size,
                              hipStream_t stream) {
    const float* feat   = (const float*)d_in[0];
    const float* desc2d = (const float*)d_in[1];
    const float* gc1W = (const float*)d_in[3];
    const float* gc1b = (const float*)d_in[4];
    const float* gc2W = (const float*)d_in[5];
    const float* gc2b = (const float*)d_in[6];
    const float* pgW  = (const float*)d_in[7];
    const float* pgb  = (const float*)d_in[8];
    const float* p2W  = (const float*)d_in[9];
    const float* p2b  = (const float*)d_in[10];
    const float* W2   = (const float*)d_in[11];
    const float* fc1W = (const float*)d_in[12];
    const float* fc2W = (const float*)d_in[14];
    const float* fc3W = (const float*)d_in[16];
    const float* fc3b = (const float*)d_in[17];
    const float* bn1g = (const float*)d_in[18];
    const float* bn1b = (const float*)d_in[19];
    const float* bn2g = (const float*)d_in[20];
    const float* bn2b = (const float*)d_in[21];
    const int* src = (const int*)d_in[22];
    const int* dst = (const int*)d_in[23];
    const int* gid = (const int*)d_in[24];
    float* out = (float*)d_out;

    char* ws = (char*)d_ws;
    size_t off = 0;
    auto alloc = [&](size_t nb) {
        void* p = ws + off;
        off = (off + nb + 255) & ~(size_t)255;
        return p;
    };
    float* t1    = (float*)alloc((size_t)NN * C1 * 4);
    float* h1    = (float*)alloc((size_t)NN * C1 * 4);
    int* cnt_in  = (int*)alloc((size_t)NN * 4);
    int* row_ptr = (int*)alloc((size_t)(NN + 1) * 4);
    int* cursor  = (int*)alloc((size_t)NN * 4);
    int* elist   = (int*)alloc((size_t)NE * 4);
    int* bsum    = (int*)alloc((size_t)256 * 4);
    int* gcnt    = (int*)alloc((size_t)NB * 4);
    float* hgs   = (float*)alloc((size_t)NB * C2 * 4);
    float* hg    = (float*)alloc((size_t)NB * C2 * 4);
    float* avec  = (float*)alloc((size_t)NB * 4);
    float* o1    = (float*)alloc((size_t)NB * HH1 * 4);
    float* st1   = (float*)alloc(2 * HH1 * 4);
    float* o2    = (float*)alloc((size_t)NB * HH2 * 4);
    float* st2   = (float*)alloc(2 * HH2 * 4);
    float* t2 = t1;   // t1 dead after h1 computed
    float* h2 = h1;   // h1 dead after t2 computed
    // fc1 scratch aliases t1 (t1/t2 dead after k_agg2; fc1 runs after k_pool)
    float* U     = t1;                                  // 512*2688*4 = 5.5 MB
    float* d1ext = t1 + (size_t)NB * NU;                // 512*204*4 = 418 KB

    hipMemsetAsync(cnt_in, 0, (size_t)NN * 4, stream);
    hipMemsetAsync(gcnt, 0, (size_t)NB * 4, stream);
    hipMemsetAsync(hgs, 0, (size_t)NB * C2 * 4, stream);

    k_count<<<(NE + 255) / 256, 256, 0, stream>>>(dst, cnt_in);
    k_gcount<<<(NN + 255) / 256, 256, 0, stream>>>(gid, gcnt);
    k_scan1<<<SCB, 256, 0, stream>>>(cnt_in, row_ptr, bsum);
    k_scan2<<<1, 256, 0, stream>>>(bsum, row_ptr);
    k_scan3<<<SCB, 256, 0, stream>>>(row_ptr, bsum, cursor);
    k_fill<<<(NE + 255) / 256, 256, 0, stream>>>(src, dst, cursor, elist);

    k_gemm1<<<512, 256, 0, stream>>>(feat, gc1W, t1);
    k_agg1<<<NN, 128, 0, stream>>>(t1, row_ptr, elist, cnt_in, gc1b, h1);

    k_gemm2<<<(NN + 15) / 16, 320, 0, stream>>>(h1, gc2W, t2);
    k_agg2<<<(NN + 11) / 12, 256, 0, stream>>>(t2, row_ptr, elist, cnt_in, gc2b, h2);

    k_pool<<<(NN * C2 + 255) / 256, 256, 0, stream>>>(h2, gid, hgs);
    k_hgdiv<<<(NB * C2 + 255) / 256, 256, 0, stream>>>(hgs, gcnt, hg);

    k_head<<<NB, 64, 0, stream>>>(hg, desc2d, pgW, pgb, p2W, p2b, W2, avec);

    k_prep<<<(NB * KDP + 255) / 256, 256, 0, stream>>>(desc2d, avec, d1ext);
    dim3 g1(16, 21);
    k_fc1<<<g1, 256, 0, stream>>>(d1ext, fc1W, U);
    k_fc1b<<<NB * HH1 / 256, 256, 0, stream>>>(U, hg, o1);

    k_bnstats<<<1, 1024, 0, stream>>>(o1, st1, HH1, NB);
    k_fc2<<<NB, 128, 0, stream>>>(o1, st1, bn1g, bn1b, fc2W, o2);
    k_bnstats<<<1, 1024, 0, stream>>>(o2, st2, HH2, NB);
    k_final<<<1, 512, 0, stream>>>(o2, st2, bn2g, bn2b, fc3W, fc3b, out);
}

// Round 6
// 342.721 us; speedup vs baseline: 2.1170x; 1.0913x over previous
//
#include <hip/hip_runtime.h>

#define NN 50000
#define NE 800000
#define NB 512
#define DIN 128
#define DD2 200
#define C1 100
#define C2 20
#define DHH 64
#define HH1 128
#define HH2 32
#define KD 201      // fusion inner dim per i (200 + 1)
#define KDP 204     // padded row stride for d1ext
#define NU 2688     // 21 * 128
#define SCB 196     // scan blocks: ceil(50000/256)

__device__ __forceinline__ unsigned short f2bf(float x) {
    unsigned u = __float_as_uint(x);
    unsigned r = (u + 0x7fffu + ((u >> 16) & 1u)) >> 16;   // RNE
    return (unsigned short)r;
}
__device__ __forceinline__ float bf_lo(unsigned u) { return __uint_as_float(u << 16); }
__device__ __forceinline__ float bf_hi(unsigned u) { return __uint_as_float(u & 0xffff0000u); }

// ---------------- CSR build ----------------
__global__ void k_count(const int* __restrict__ dst, int* __restrict__ cnt) {
    int e = blockIdx.x * 256 + threadIdx.x;
    if (e < NE) atomicAdd(&cnt[dst[e]], 1);
}

__global__ void k_gcount(const int* __restrict__ gid, int* __restrict__ gcnt) {
    int n = blockIdx.x * 256 + threadIdx.x;
    if (n < NN) atomicAdd(&gcnt[gid[n]], 1);
}

__global__ void k_scan1(const int* __restrict__ cnt, int* __restrict__ row_ptr,
                        int* __restrict__ bsum) {
    __shared__ int wsum[4];
    const int tid = threadIdx.x;          // 256
    const int lane = tid & 63, wid = tid >> 6;
    int i = blockIdx.x * 256 + tid;
    int v = (i < NN) ? cnt[i] : 0;
    int x = v;
    #pragma unroll
    for (int d = 1; d < 64; d <<= 1) {
        int t = __shfl_up(x, d, 64);
        if (lane >= d) x += t;
    }
    if (lane == 63) wsum[wid] = x;
    __syncthreads();
    int wpref = 0;
    #pragma unroll
    for (int w = 0; w < 4; ++w) if (w < wid) wpref += wsum[w];
    if (i < NN) row_ptr[i] = wpref + x - v;
    if (tid == 255) bsum[blockIdx.x] = wpref + x;
}

__global__ void k_scan2(int* __restrict__ bsum, int* __restrict__ row_ptr) {
    __shared__ int wsum[4];
    const int tid = threadIdx.x;
    const int lane = tid & 63, wid = tid >> 6;
    int v = (tid < SCB) ? bsum[tid] : 0;
    int x = v;
    #pragma unroll
    for (int d = 1; d < 64; d <<= 1) {
        int t = __shfl_up(x, d, 64);
        if (lane >= d) x += t;
    }
    if (lane == 63) wsum[wid] = x;
    __syncthreads();
    int wpref = 0;
    #pragma unroll
    for (int w = 0; w < 4; ++w) if (w < wid) wpref += wsum[w];
    if (tid < SCB) bsum[tid] = wpref + x - v;
    if (tid == 255) row_ptr[NN] = wpref + x;
}

__global__ void k_scan3(int* __restrict__ row_ptr, const int* __restrict__ bsum,
                        int* __restrict__ cursor) {
    int i = blockIdx.x * 256 + threadIdx.x;
    if (i < NN) {
        int e = row_ptr[i] + bsum[blockIdx.x];
        row_ptr[i] = e;
        cursor[i] = e;
    }
}

__global__ void k_fill(const int* __restrict__ src, const int* __restrict__ dst,
                       int* __restrict__ cursor, int* __restrict__ elist) {
    int e = blockIdx.x * 256 + threadIdx.x;
    if (e < NE) {
        int p = atomicAdd(&cursor[dst[e]], 1);
        elist[p] = src[e];
    }
}

// ---------------- GCN layer 1 GEMM ----------------
// t1b[n][j] = packed bf16 pair (channels 2j, 2j+1) of feat@gc1_W
__global__ __launch_bounds__(256, 2) void k_gemm1(const float* __restrict__ feat,
                                                  const float* __restrict__ W,
                                                  unsigned* __restrict__ t1b) {
    __shared__ float sWT[C1 * DIN];      // sWT[col*128 + (k ^ ((col&7)<<2))]
    __shared__ float sf[32][DIN + 4];
    const int tid = threadIdx.x;
    for (int idx = tid; idx < DIN * C1; idx += 256) {
        int k = idx / C1, col = idx % C1;
        sWT[col * DIN + (k ^ ((col & 7) << 2))] = W[idx];
    }
    const int j = tid & 63;              // active j<50: cols 2j, 2j+1
    const int rg = tid >> 6;             // 0..3
    const bool act = j < 50;
    const int c0 = 2 * j, c1 = 2 * j + 1;
    const int swz0 = (c0 & 7) << 2, swz1 = (c1 & 7) << 2;

    for (int n0 = blockIdx.x * 32; n0 < NN; n0 += gridDim.x * 32) {
        __syncthreads();
        {
            int r = tid >> 3, so = (tid & 7) * 16;
            int n = n0 + r;
            float4* dstp = (float4*)&sf[r][so];
            if (n < NN) {
                const float4* srcp = (const float4*)(feat + (size_t)n * DIN + so);
                dstp[0] = srcp[0]; dstp[1] = srcp[1]; dstp[2] = srcp[2]; dstp[3] = srcp[3];
            } else {
                float4 z = {0.f, 0.f, 0.f, 0.f};
                dstp[0] = z; dstp[1] = z; dstp[2] = z; dstp[3] = z;
            }
        }
        __syncthreads();
        if (act) {
            float acc0[8], acc1[8];
            #pragma unroll
            for (int r = 0; r < 8; ++r) { acc0[r] = 0.f; acc1[r] = 0.f; }
            #pragma unroll 4
            for (int kc = 0; kc < DIN; kc += 4) {
                float4 w0 = *(const float4*)&sWT[c0 * DIN + (kc ^ swz0)];
                float4 w1 = *(const float4*)&sWT[c1 * DIN + (kc ^ swz1)];
                #pragma unroll
                for (int r = 0; r < 8; ++r) {
                    float4 a = *(const float4*)&sf[rg * 8 + r][kc];
                    acc0[r] += a.x * w0.x; acc0[r] += a.y * w0.y;
                    acc0[r] += a.z * w0.z; acc0[r] += a.w * w0.w;
                    acc1[r] += a.x * w1.x; acc1[r] += a.y * w1.y;
                    acc1[r] += a.z * w1.z; acc1[r] += a.w * w1.w;
                }
            }
            #pragma unroll
            for (int r = 0; r < 8; ++r) {
                int n = n0 + rg * 8 + r;
                if (n < NN) {
                    unsigned pk = (unsigned)f2bf(acc0[r]) | ((unsigned)f2bf(acc1[r]) << 16);
                    t1b[(size_t)n * 50 + j] = pk;
                }
            }
        }
    }
}

// ---------------- fused: agg1 (mean+bias+relu) + gemm2 -> t2 ----------------
// block = 256 = 4 waves; wave w handles node blockIdx.x*4+w; lane l<50 gathers 2 channels.
__global__ void k_agg1g2(const unsigned* __restrict__ t1b, const int* __restrict__ row_ptr,
                         const int* __restrict__ elist, const float* __restrict__ b1,
                         const float* __restrict__ W2, float* __restrict__ t2) {
    __shared__ float sW2[C1 * C2];       // 8 KB
    __shared__ float sh1[4][C1];
    const int tid = threadIdx.x;
    for (int idx = tid; idx < C1 * C2; idx += 256) sW2[idx] = W2[idx];
    const int w = tid >> 6, l = tid & 63;
    const int n = blockIdx.x * 4 + w;
    if (n < NN) {
        if (l < 50) {
            int e0 = row_ptr[n], e1 = row_ptr[n + 1];
            float acc0 = 0.f, acc1 = 0.f;
            int e = e0;
            for (; e + 3 < e1; e += 4) {
                int s0 = elist[e], s1 = elist[e + 1], s2 = elist[e + 2], s3 = elist[e + 3];
                unsigned u0 = t1b[(size_t)s0 * 50 + l];
                unsigned u1 = t1b[(size_t)s1 * 50 + l];
                unsigned u2 = t1b[(size_t)s2 * 50 + l];
                unsigned u3 = t1b[(size_t)s3 * 50 + l];
                acc0 += bf_lo(u0); acc1 += bf_hi(u0);
                acc0 += bf_lo(u1); acc1 += bf_hi(u1);
                acc0 += bf_lo(u2); acc1 += bf_hi(u2);
                acc0 += bf_lo(u3); acc1 += bf_hi(u3);
            }
            for (; e < e1; ++e) {
                unsigned u = t1b[(size_t)elist[e] * 50 + l];
                acc0 += bf_lo(u); acc1 += bf_hi(u);
            }
            int deg = e1 - e0;
            float d = (float)(deg > 0 ? deg : 1);
            float v0 = acc0 / d + b1[2 * l];
            float v1 = acc1 / d + b1[2 * l + 1];
            sh1[w][2 * l]     = v0 > 0.f ? v0 : 0.f;
            sh1[w][2 * l + 1] = v1 > 0.f ? v1 : 0.f;
        }
    }
    __syncthreads();
    if (n < NN && l < C2) {
        float acc = 0.f;
        #pragma unroll 4
        for (int k = 0; k < C1; ++k) acc += sh1[w][k] * sW2[k * C2 + l];
        t2[(size_t)n * C2 + l] = acc;
    }
}

// ---------------- fused: agg2 (mean+bias+relu) + graph pool (atomic) ----------------
__global__ void k_agg2p(const float* __restrict__ t2, const int* __restrict__ row_ptr,
                        const int* __restrict__ elist, const float* __restrict__ bias,
                        const int* __restrict__ gid, float* __restrict__ hgs) {
    int ln = threadIdx.x / C2, c = threadIdx.x % C2;
    if (ln >= 12) return;
    int n = blockIdx.x * 12 + ln;
    if (n >= NN) return;
    int e0 = row_ptr[n], e1 = row_ptr[n + 1];
    float acc = 0.f;
    int e = e0;
    for (; e + 1 < e1; e += 2) {
        int s0 = elist[e], s1 = elist[e + 1];
        acc += t2[(size_t)s0 * C2 + c];
        acc += t2[(size_t)s1 * C2 + c];
    }
    for (; e < e1; ++e) acc += t2[(size_t)elist[e] * C2 + c];
    int deg = e1 - e0;
    float d = (float)(deg > 0 ? deg : 1);
    float v = acc / d + bias[c];
    v = v > 0.f ? v : 0.f;
    atomicAdd(&hgs[gid[n] * C2 + c], v);
}

__global__ void k_hgdiv(const float* __restrict__ hgs, const int* __restrict__ gcnt,
                        float* __restrict__ hg) {
    int idx = blockIdx.x * 256 + threadIdx.x;
    if (idx < NB * C2) {
        float d = (float)gcnt[idx / C2]; d = d > 1.f ? d : 1.f;
        hg[idx] = hgs[idx] / d;
    }
}

// ---------------- attention head ----------------
__global__ void k_head(const float* __restrict__ hg, const float* __restrict__ desc2d,
                       const float* __restrict__ pgW, const float* __restrict__ pgb,
                       const float* __restrict__ p2W, const float* __restrict__ p2b,
                       const float* __restrict__ W2, float* __restrict__ a_out) {
    __shared__ float shg[C2];
    __shared__ float sg[DHH];
    int b = blockIdx.x, j = threadIdx.x;   // 64 threads
    if (j < C2) shg[j] = hg[b * C2 + j];
    __syncthreads();
    float hgj = pgb[j];
    #pragma unroll
    for (int k = 0; k < C2; ++k) hgj += shg[k] * pgW[k * DHH + j];
    float hdj = p2b[j];
    #pragma unroll 4
    for (int k = 0; k < DD2; ++k) hdj += desc2d[b * DD2 + k] * p2W[k * DHH + j];
    sg[j] = hgj;
    __syncthreads();
    float tj = 0.f;
    #pragma unroll 4
    for (int k = 0; k < DHH; ++k) tj += sg[k] * W2[k * DHH + j];
    float v = tj * hdj;
    #pragma unroll
    for (int off = 32; off; off >>= 1) v += __shfl_xor(v, off, 64);
    if (j == 0) a_out[b] = 1.f / (1.f + expf(-v));
}

// ---------------- fc1 via rank-1 factorization ----------------
__global__ void k_prep(const float* __restrict__ desc2d, const float* __restrict__ a,
                       float* __restrict__ d1ext) {
    int idx = blockIdx.x * 256 + threadIdx.x;
    if (idx < NB * KDP) {
        int b = idx / KDP, k = idx % KDP;
        float v = (k < DD2) ? a[b] * desc2d[b * DD2 + k] : (k == DD2 ? 1.f : 0.f);
        d1ext[idx] = v;
    }
}

__global__ __launch_bounds__(256, 2) void k_fc1(const float* __restrict__ d1ext,
                                                const float* __restrict__ W1,
                                                float* __restrict__ U) {
    __shared__ float S[64][KDP];
    const int i = blockIdx.y;
    const int bt = blockIdx.x >> 1;
    const int half = blockIdx.x & 1;
    const int tid = threadIdx.x;
    const int c = tid & 31;
    const int rg = tid >> 5;

    {
        const float4* srcp = (const float4*)(d1ext + (size_t)bt * 64 * KDP);
        float4* dstp = (float4*)&S[0][0];
        for (int idx = tid; idx < 64 * (KDP / 4); idx += 256) dstp[idx] = srcp[idx];
    }
    __syncthreads();

    float acc[8][2];
    #pragma unroll
    for (int r = 0; r < 8; ++r) { acc[r][0] = 0.f; acc[r][1] = 0.f; }

    const float* Wb = W1 + (size_t)i * (KD * HH1) + half * 64 + c;
    for (int k = 0; k < 200; k += 4) {
        const float* Wk = Wb + (size_t)k * HH1;
        float w0[2], w1[2], w2[2], w3[2];
        #pragma unroll
        for (int m = 0; m < 2; ++m) {
            w0[m] = Wk[32 * m];
            w1[m] = Wk[HH1 + 32 * m];
            w2[m] = Wk[2 * HH1 + 32 * m];
            w3[m] = Wk[3 * HH1 + 32 * m];
        }
        #pragma unroll
        for (int r = 0; r < 8; ++r) {
            float4 a4 = *(const float4*)&S[rg * 8 + r][k];
            #pragma unroll
            for (int m = 0; m < 2; ++m)
                acc[r][m] += a4.x * w0[m] + a4.y * w1[m] + a4.z * w2[m] + a4.w * w3[m];
        }
    }
    {
        const float* Wk = Wb + (size_t)200 * HH1;
        float wl0 = Wk[0], wl1 = Wk[32];
        #pragma unroll
        for (int r = 0; r < 8; ++r) {
            float av = S[rg * 8 + r][200];
            acc[r][0] += av * wl0;
            acc[r][1] += av * wl1;
        }
    }
    #pragma unroll
    for (int r = 0; r < 8; ++r) {
        int b = bt * 64 + rg * 8 + r;
        float* Ur = U + (size_t)b * NU + i * HH1 + half * 64 + c;
        Ur[0] = acc[r][0];
        Ur[32] = acc[r][1];
    }
}

__global__ void k_fc1b(const float* __restrict__ U, const float* __restrict__ hg,
                       float* __restrict__ o1) {
    int idx = blockIdx.x * 256 + threadIdx.x;   // 65536
    int b = idx >> 7, j = idx & 127;
    const float* Ub = U + (size_t)b * NU + j;
    const float* hgb = hg + b * C2;
    float acc = Ub[20 * HH1];
    #pragma unroll
    for (int i = 0; i < 20; ++i) acc += hgb[i] * Ub[i * HH1];
    o1[idx] = acc;
}

// ---------------- batch-norm stats ----------------
__global__ void k_bnstats(const float* __restrict__ x, float* __restrict__ stats,
                          int ncols, int nrows) {
    __shared__ float sh[1024], sh2[1024];
    const int tid = threadIdx.x;
    const int j = tid % ncols;
    const int r = tid / ncols;
    const int R = 1024 / ncols;
    float s = 0.f, s2 = 0.f;
    for (int b = r; b < nrows; b += R) {
        float v = x[b * ncols + j];
        s += v; s2 += v * v;
    }
    sh[tid] = s; sh2[tid] = s2;
    __syncthreads();
    if (r == 0) {
        for (int q = 1; q < R; ++q) { s += sh[q * ncols + j]; s2 += sh2[q * ncols + j]; }
        float mu = s / nrows;
        float var = s2 / nrows - mu * mu;
        stats[j] = mu;
        stats[ncols + j] = rsqrtf(var + 1e-5f);
    }
}

// ---------------- fc2 (bn1 + relu fused) ----------------
__global__ void k_fc2(const float* __restrict__ o1, const float* __restrict__ st1,
                      const float* __restrict__ g, const float* __restrict__ beta,
                      const float* __restrict__ W, float* __restrict__ o2) {
    __shared__ float r[HH1];
    __shared__ float part[4][HH2];
    int b = blockIdx.x;
    int tid = threadIdx.x;   // 128
    float v = o1[b * HH1 + tid];
    float nv = (v - st1[tid]) * st1[HH1 + tid] * g[tid] + beta[tid];
    r[tid] = fmaxf(nv, 0.f);
    __syncthreads();
    int m = tid & 31, p = tid >> 5;
    float acc = 0.f;
    #pragma unroll 4
    for (int j = p * 32; j < p * 32 + 32; ++j) acc += r[j] * W[j * HH2 + m];
    part[p][m] = acc;
    __syncthreads();
    if (tid < HH2) o2[b * HH2 + tid] = part[0][tid] + part[1][tid] + part[2][tid] + part[3][tid];
}

// ---------------- bn2 + relu + fc3 ----------------
__global__ void k_final(const float* __restrict__ o2, const float* __restrict__ st2,
                        const float* __restrict__ g, const float* __restrict__ beta,
                        const float* __restrict__ W3, const float* __restrict__ b3,
                        float* __restrict__ out) {
    int b = threadIdx.x;    // 512
    if (b < NB) {
        float acc = b3[0];
        #pragma unroll 4
        for (int m = 0; m < HH2; ++m) {
            float v = o2[b * HH2 + m];
            float nv = (v - st2[m]) * st2[HH2 + m] * g[m] + beta[m];
            acc += fmaxf(nv, 0.f) * W3[m];
        }
        out[b] = acc;
    }
}

extern "C" void kernel_launch(void* const* d_in, const int* in_sizes, int n_in,
                              void* d_out, int out_size, void* d_ws, size_t ws_size,
                              hipStream_t stream) {
    const float* feat   = (const float*)d_in[0];
    const float* desc2d = (const float*)d_in[1];
    const float* gc1W = (const float*)d_in[3];
    const float* gc1b = (const float*)d_in[4];
    const float* gc2W = (const float*)d_in[5];
    const float* gc2b = (const float*)d_in[6];
    const float* pgW  = (const float*)d_in[7];
    const float* pgb  = (const float*)d_in[8];
    const float* p2W  = (const float*)d_in[9];
    const float* p2b  = (const float*)d_in[10];
    const float* W2   = (const float*)d_in[11];
    const float* fc1W = (const float*)d_in[12];
    const float* fc2W = (const float*)d_in[14];
    const float* fc3W = (const float*)d_in[16];
    const float* fc3b = (const float*)d_in[17];
    const float* bn1g = (const float*)d_in[18];
    const float* bn1b = (const float*)d_in[19];
    const float* bn2g = (const float*)d_in[20];
    const float* bn2b = (const float*)d_in[21];
    const int* src = (const int*)d_in[22];
    const int* dst = (const int*)d_in[23];
    const int* gid = (const int*)d_in[24];
    float* out = (float*)d_out;

    char* ws = (char*)d_ws;
    size_t off = 0;
    auto alloc = [&](size_t nb) {
        void* p = ws + off;
        off = (off + nb + 255) & ~(size_t)255;
        return p;
    };
    unsigned* t1b = (unsigned*)alloc((size_t)NN * 50 * 4);   // 10 MB packed bf16
    float* t2    = (float*)alloc((size_t)NN * C2 * 4);       // 4 MB
    int* cnt_in  = (int*)alloc((size_t)NN * 4);
    int* row_ptr = (int*)alloc((size_t)(NN + 1) * 4);
    int* cursor  = (int*)alloc((size_t)NN * 4);
    int* elist   = (int*)alloc((size_t)NE * 4);
    int* bsum    = (int*)alloc((size_t)256 * 4);
    int* gcnt    = (int*)alloc((size_t)NB * 4);
    float* hgs   = (float*)alloc((size_t)NB * C2 * 4);
    float* hg    = (float*)alloc((size_t)NB * C2 * 4);
    float* avec  = (float*)alloc((size_t)NB * 4);
    float* o1    = (float*)alloc((size_t)NB * HH1 * 4);
    float* st1   = (float*)alloc(2 * HH1 * 4);
    float* o2    = (float*)alloc((size_t)NB * HH2 * 4);
    float* st2   = (float*)alloc(2 * HH2 * 4);
    // fc1 scratch aliases t1b (dead after k_agg1g2)
    float* U     = (float*)t1b;                              // 5.5 MB < 10 MB
    float* d1ext = U + (size_t)NB * NU;

    hipMemsetAsync(cnt_in, 0, (size_t)NN * 4, stream);
    hipMemsetAsync(gcnt, 0, (size_t)NB * 4, stream);
    hipMemsetAsync(hgs, 0, (size_t)NB * C2 * 4, stream);

    k_count<<<(NE + 255) / 256, 256, 0, stream>>>(dst, cnt_in);
    k_gcount<<<(NN + 255) / 256, 256, 0, stream>>>(gid, gcnt);
    k_scan1<<<SCB, 256, 0, stream>>>(cnt_in, row_ptr, bsum);
    k_scan2<<<1, 256, 0, stream>>>(bsum, row_ptr);
    k_scan3<<<SCB, 256, 0, stream>>>(row_ptr, bsum, cursor);
    k_fill<<<(NE + 255) / 256, 256, 0, stream>>>(src, dst, cursor, elist);

    k_gemm1<<<512, 256, 0, stream>>>(feat, gc1W, t1b);
    k_agg1g2<<<(NN + 3) / 4, 256, 0, stream>>>(t1b, row_ptr, elist, gc1b, gc2W, t2);
    k_agg2p<<<(NN + 11) / 12, 256, 0, stream>>>(t2, row_ptr, elist, gc2b, gid, hgs);
    k_hgdiv<<<(NB * C2 + 255) / 256, 256, 0, stream>>>(hgs, gcnt, hg);

    k_head<<<NB, 64, 0, stream>>>(hg, desc2d, pgW, pgb, p2W, p2b, W2, avec);

    k_prep<<<(NB * KDP + 255) / 256, 256, 0, stream>>>(desc2d, avec, d1ext);
    dim3 g1(16, 21);
    k_fc1<<<g1, 256, 0, stream>>>(d1ext, fc1W, U);
    k_fc1b<<<NB * HH1 / 256, 256, 0, stream>>>(U, hg, o1);

    k_bnstats<<<1, 1024, 0, stream>>>(o1, st1, HH1, NB);
    k_fc2<<<NB, 128, 0, stream>>>(o1, st1, bn1g, bn1b, fc2W, o2);
    k_bnstats<<<1, 1024, 0, stream>>>(o2, st2, HH2, NB);
    k_final<<<1, 512, 0, stream>>>(o2, st2, bn2g, bn2b, fc3W, fc3b, out);
}

// Round 7
// 333.894 us; speedup vs baseline: 2.1730x; 1.0264x over previous
//
#include <hip/hip_runtime.h>

#define NN 50000
#define NE 800000
#define NB 512
#define DIN 128
#define DD2 200
#define C1 100
#define C2 20
#define DHH 64
#define HH1 128
#define HH2 32
#define KD 201      // fusion inner dim per i (200 + 1)
#define KDP 204     // padded row stride for d1ext
#define NU 2688     // 21 * 128
#define SCB 196     // scan blocks: ceil(50000/256)

__device__ __forceinline__ unsigned short f2bf(float x) {
    unsigned u = __float_as_uint(x);
    unsigned r = (u + 0x7fffu + ((u >> 16) & 1u)) >> 16;   // RNE
    return (unsigned short)r;
}
__device__ __forceinline__ float bf_lo(unsigned u) { return __uint_as_float(u << 16); }
__device__ __forceinline__ float bf_hi(unsigned u) { return __uint_as_float(u & 0xffff0000u); }

// ---------------- CSR build ----------------
__global__ void k_countg(const int* __restrict__ dst, int* __restrict__ cnt,
                         const int* __restrict__ gid, int* __restrict__ gcnt) {
    int i = blockIdx.x * 256 + threadIdx.x;
    if (i < NE) atomicAdd(&cnt[dst[i]], 1);
    if (i < NN) atomicAdd(&gcnt[gid[i]], 1);
}

__global__ void k_scan1(const int* __restrict__ cnt, int* __restrict__ row_ptr,
                        int* __restrict__ bsum) {
    __shared__ int wsum[4];
    const int tid = threadIdx.x;          // 256
    const int lane = tid & 63, wid = tid >> 6;
    int i = blockIdx.x * 256 + tid;
    int v = (i < NN) ? cnt[i] : 0;
    int x = v;
    #pragma unroll
    for (int d = 1; d < 64; d <<= 1) {
        int t = __shfl_up(x, d, 64);
        if (lane >= d) x += t;
    }
    if (lane == 63) wsum[wid] = x;
    __syncthreads();
    int wpref = 0;
    #pragma unroll
    for (int w = 0; w < 4; ++w) if (w < wid) wpref += wsum[w];
    if (i < NN) row_ptr[i] = wpref + x - v;
    if (tid == 255) bsum[blockIdx.x] = wpref + x;
}

__global__ void k_scan2(int* __restrict__ bsum, int* __restrict__ row_ptr) {
    __shared__ int wsum[4];
    const int tid = threadIdx.x;
    const int lane = tid & 63, wid = tid >> 6;
    int v = (tid < SCB) ? bsum[tid] : 0;
    int x = v;
    #pragma unroll
    for (int d = 1; d < 64; d <<= 1) {
        int t = __shfl_up(x, d, 64);
        if (lane >= d) x += t;
    }
    if (lane == 63) wsum[wid] = x;
    __syncthreads();
    int wpref = 0;
    #pragma unroll
    for (int w = 0; w < 4; ++w) if (w < wid) wpref += wsum[w];
    if (tid < SCB) bsum[tid] = wpref + x - v;
    if (tid == 255) row_ptr[NN] = wpref + x;
}

__global__ void k_scan3(int* __restrict__ row_ptr, const int* __restrict__ bsum,
                        int* __restrict__ cursor) {
    int i = blockIdx.x * 256 + threadIdx.x;
    if (i < NN) {
        int e = row_ptr[i] + bsum[blockIdx.x];
        row_ptr[i] = e;
        cursor[i] = e;
    }
}

__global__ void k_fill(const int* __restrict__ src, const int* __restrict__ dst,
                       int* __restrict__ cursor, int* __restrict__ elist) {
    int e = blockIdx.x * 256 + threadIdx.x;
    if (e < NE) {
        int p = atomicAdd(&cursor[dst[e]], 1);
        elist[p] = src[e];
    }
}

// ---------------- GCN layer 1 GEMM ----------------
// t1b[n][j] = packed bf16 pair (channels 2j, 2j+1) of feat@gc1_W
__global__ __launch_bounds__(256, 2) void k_gemm1(const float* __restrict__ feat,
                                                  const float* __restrict__ W,
                                                  unsigned* __restrict__ t1b) {
    __shared__ float sWT[C1 * DIN];      // sWT[col*128 + (k ^ ((col&7)<<2))]
    __shared__ float sf[32][DIN + 4];
    const int tid = threadIdx.x;
    for (int idx = tid; idx < DIN * C1; idx += 256) {
        int k = idx / C1, col = idx % C1;
        sWT[col * DIN + (k ^ ((col & 7) << 2))] = W[idx];
    }
    const int j = tid & 63;              // active j<50: cols 2j, 2j+1
    const int rg = tid >> 6;             // 0..3
    const bool act = j < 50;
    const int c0 = 2 * j, c1 = 2 * j + 1;
    const int swz0 = (c0 & 7) << 2, swz1 = (c1 & 7) << 2;

    for (int n0 = blockIdx.x * 32; n0 < NN; n0 += gridDim.x * 32) {
        __syncthreads();
        {
            int r = tid >> 3, so = (tid & 7) * 16;
            int n = n0 + r;
            float4* dstp = (float4*)&sf[r][so];
            if (n < NN) {
                const float4* srcp = (const float4*)(feat + (size_t)n * DIN + so);
                dstp[0] = srcp[0]; dstp[1] = srcp[1]; dstp[2] = srcp[2]; dstp[3] = srcp[3];
            } else {
                float4 z = {0.f, 0.f, 0.f, 0.f};
                dstp[0] = z; dstp[1] = z; dstp[2] = z; dstp[3] = z;
            }
        }
        __syncthreads();
        if (act) {
            float acc0[8], acc1[8];
            #pragma unroll
            for (int r = 0; r < 8; ++r) { acc0[r] = 0.f; acc1[r] = 0.f; }
            #pragma unroll 4
            for (int kc = 0; kc < DIN; kc += 4) {
                float4 w0 = *(const float4*)&sWT[c0 * DIN + (kc ^ swz0)];
                float4 w1 = *(const float4*)&sWT[c1 * DIN + (kc ^ swz1)];
                #pragma unroll
                for (int r = 0; r < 8; ++r) {
                    float4 a = *(const float4*)&sf[rg * 8 + r][kc];
                    acc0[r] += a.x * w0.x; acc0[r] += a.y * w0.y;
                    acc0[r] += a.z * w0.z; acc0[r] += a.w * w0.w;
                    acc1[r] += a.x * w1.x; acc1[r] += a.y * w1.y;
                    acc1[r] += a.z * w1.z; acc1[r] += a.w * w1.w;
                }
            }
            #pragma unroll
            for (int r = 0; r < 8; ++r) {
                int n = n0 + rg * 8 + r;
                if (n < NN) {
                    unsigned pk = (unsigned)f2bf(acc0[r]) | ((unsigned)f2bf(acc1[r]) << 16);
                    t1b[(size_t)n * 50 + j] = pk;
                }
            }
        }
    }
}

// ---------------- agg1: gather-mean + bias + relu -> packed bf16 h1b ----------------
// wave per node, lane l<50 handles channels 2l,2l+1; 8-deep load batches.
__global__ __launch_bounds__(256) void k_agg1(const unsigned* __restrict__ t1b,
                                              const int* __restrict__ row_ptr,
                                              const int* __restrict__ elist,
                                              const float* __restrict__ b1,
                                              unsigned* __restrict__ h1b) {
    const int tid = threadIdx.x;
    const int w = tid >> 6, l = tid & 63;
    const int n = blockIdx.x * 4 + w;
    if (n >= NN || l >= 50) return;
    const int e0 = row_ptr[n], e1 = row_ptr[n + 1];
    float acc0 = 0.f, acc1 = 0.f;
    int e = e0;
    for (; e + 7 < e1; e += 8) {
        int s0 = elist[e],     s1 = elist[e + 1], s2 = elist[e + 2], s3 = elist[e + 3];
        int s4 = elist[e + 4], s5 = elist[e + 5], s6 = elist[e + 6], s7 = elist[e + 7];
        unsigned u0 = t1b[s0 * 50 + l];
        unsigned u1 = t1b[s1 * 50 + l];
        unsigned u2 = t1b[s2 * 50 + l];
        unsigned u3 = t1b[s3 * 50 + l];
        unsigned u4 = t1b[s4 * 50 + l];
        unsigned u5 = t1b[s5 * 50 + l];
        unsigned u6 = t1b[s6 * 50 + l];
        unsigned u7 = t1b[s7 * 50 + l];
        acc0 += bf_lo(u0); acc1 += bf_hi(u0);
        acc0 += bf_lo(u1); acc1 += bf_hi(u1);
        acc0 += bf_lo(u2); acc1 += bf_hi(u2);
        acc0 += bf_lo(u3); acc1 += bf_hi(u3);
        acc0 += bf_lo(u4); acc1 += bf_hi(u4);
        acc0 += bf_lo(u5); acc1 += bf_hi(u5);
        acc0 += bf_lo(u6); acc1 += bf_hi(u6);
        acc0 += bf_lo(u7); acc1 += bf_hi(u7);
    }
    for (; e + 3 < e1; e += 4) {
        int s0 = elist[e], s1 = elist[e + 1], s2 = elist[e + 2], s3 = elist[e + 3];
        unsigned u0 = t1b[s0 * 50 + l];
        unsigned u1 = t1b[s1 * 50 + l];
        unsigned u2 = t1b[s2 * 50 + l];
        unsigned u3 = t1b[s3 * 50 + l];
        acc0 += bf_lo(u0); acc1 += bf_hi(u0);
        acc0 += bf_lo(u1); acc1 += bf_hi(u1);
        acc0 += bf_lo(u2); acc1 += bf_hi(u2);
        acc0 += bf_lo(u3); acc1 += bf_hi(u3);
    }
    for (; e < e1; ++e) {
        unsigned u = t1b[elist[e] * 50 + l];
        acc0 += bf_lo(u); acc1 += bf_hi(u);
    }
    int deg = e1 - e0;
    float d = (float)(deg > 0 ? deg : 1);
    float v0 = fmaxf(acc0 / d + b1[2 * l], 0.f);
    float v1 = fmaxf(acc1 / d + b1[2 * l + 1], 0.f);
    h1b[n * 50 + l] = (unsigned)f2bf(v0) | ((unsigned)f2bf(v1) << 16);
}

// ---------------- GCN layer 2 GEMM: t2 = h1 @ gc2_W ----------------
__global__ void k_gemm2(const unsigned* __restrict__ h1b, const float* __restrict__ W,
                        float* __restrict__ t2) {
    __shared__ float sW[C1 * C2];       // 8 KB
    __shared__ float sr[16][C1];        // 6.4 KB
    for (int idx = threadIdx.x; idx < C1 * C2; idx += 320) sW[idx] = W[idx];
    int ln = threadIdx.x / C2, j = threadIdx.x % C2;   // ln<16
    int n0 = blockIdx.x * 16;
    for (int idx = threadIdx.x; idx < 16 * 50; idx += 320) {
        int r = idx / 50, c = idx % 50;
        int n = n0 + r;
        unsigned u = (n < NN) ? h1b[n * 50 + c] : 0u;
        sr[r][2 * c] = bf_lo(u);
        sr[r][2 * c + 1] = bf_hi(u);
    }
    __syncthreads();
    int n = n0 + ln;
    if (n < NN && ln < 16) {
        float acc = 0.f;
        #pragma unroll 4
        for (int k = 0; k < C1; ++k) acc += sr[ln][k] * sW[k * C2 + j];
        t2[(size_t)n * C2 + j] = acc;
    }
}

// ---------------- fused: agg2 (mean+bias+relu) + graph pool (atomic) ----------------
__global__ void k_agg2p(const float* __restrict__ t2, const int* __restrict__ row_ptr,
                        const int* __restrict__ elist, const float* __restrict__ bias,
                        const int* __restrict__ gid, float* __restrict__ hgs) {
    int ln = threadIdx.x / C2, c = threadIdx.x % C2;
    if (ln >= 12) return;
    int n = blockIdx.x * 12 + ln;
    if (n >= NN) return;
    int e0 = row_ptr[n], e1 = row_ptr[n + 1];
    float acc = 0.f;
    int e = e0;
    for (; e + 1 < e1; e += 2) {
        int s0 = elist[e], s1 = elist[e + 1];
        acc += t2[(size_t)s0 * C2 + c];
        acc += t2[(size_t)s1 * C2 + c];
    }
    for (; e < e1; ++e) acc += t2[(size_t)elist[e] * C2 + c];
    int deg = e1 - e0;
    float d = (float)(deg > 0 ? deg : 1);
    float v = acc / d + bias[c];
    v = v > 0.f ? v : 0.f;
    atomicAdd(&hgs[gid[n] * C2 + c], v);
}

// ---------------- fused per-graph tail: hg div + attention head + d1ext prep ----------------
__global__ void k_headp(const float* __restrict__ hgs, const int* __restrict__ gcnt,
                        const float* __restrict__ desc2d,
                        const float* __restrict__ pgW, const float* __restrict__ pgb,
                        const float* __restrict__ p2W, const float* __restrict__ p2b,
                        const float* __restrict__ W2,
                        float* __restrict__ hg, float* __restrict__ d1ext) {
    __shared__ float shg[C2];
    __shared__ float sg[DHH];
    __shared__ float sa;
    int b = blockIdx.x, j = threadIdx.x;   // 64 threads
    if (j < C2) {
        float d = (float)gcnt[b]; d = d > 1.f ? d : 1.f;
        float v = hgs[b * C2 + j] / d;
        hg[b * C2 + j] = v;
        shg[j] = v;
    }
    __syncthreads();
    float hgj = pgb[j];
    #pragma unroll
    for (int k = 0; k < C2; ++k) hgj += shg[k] * pgW[k * DHH + j];
    float hdj = p2b[j];
    #pragma unroll 4
    for (int k = 0; k < DD2; ++k) hdj += desc2d[b * DD2 + k] * p2W[k * DHH + j];
    sg[j] = hgj;
    __syncthreads();
    float tj = 0.f;
    #pragma unroll 4
    for (int k = 0; k < DHH; ++k) tj += sg[k] * W2[k * DHH + j];
    float v = tj * hdj;
    #pragma unroll
    for (int off = 32; off; off >>= 1) v += __shfl_xor(v, off, 64);
    if (j == 0) sa = 1.f / (1.f + expf(-v));
    __syncthreads();
    float a = sa;
    for (int k = j; k < KDP; k += 64) {
        float vv = (k < DD2) ? a * desc2d[b * DD2 + k] : (k == DD2 ? 1.f : 0.f);
        d1ext[b * KDP + k] = vv;
    }
}

// ---------------- fc1 via rank-1 factorization ----------------
__global__ __launch_bounds__(256, 2) void k_fc1(const float* __restrict__ d1ext,
                                                const float* __restrict__ W1,
                                                float* __restrict__ U) {
    __shared__ float S[64][KDP];
    const int i = blockIdx.y;
    const int bt = blockIdx.x >> 1;
    const int half = blockIdx.x & 1;
    const int tid = threadIdx.x;
    const int c = tid & 31;
    const int rg = tid >> 5;

    {
        const float4* srcp = (const float4*)(d1ext + (size_t)bt * 64 * KDP);
        float4* dstp = (float4*)&S[0][0];
        for (int idx = tid; idx < 64 * (KDP / 4); idx += 256) dstp[idx] = srcp[idx];
    }
    __syncthreads();

    float acc[8][2];
    #pragma unroll
    for (int r = 0; r < 8; ++r) { acc[r][0] = 0.f; acc[r][1] = 0.f; }

    const float* Wb = W1 + (size_t)i * (KD * HH1) + half * 64 + c;
    for (int k = 0; k < 200; k += 4) {
        const float* Wk = Wb + (size_t)k * HH1;
        float w0[2], w1[2], w2[2], w3[2];
        #pragma unroll
        for (int m = 0; m < 2; ++m) {
            w0[m] = Wk[32 * m];
            w1[m] = Wk[HH1 + 32 * m];
            w2[m] = Wk[2 * HH1 + 32 * m];
            w3[m] = Wk[3 * HH1 + 32 * m];
        }
        #pragma unroll
        for (int r = 0; r < 8; ++r) {
            float4 a4 = *(const float4*)&S[rg * 8 + r][k];
            #pragma unroll
            for (int m = 0; m < 2; ++m)
                acc[r][m] += a4.x * w0[m] + a4.y * w1[m] + a4.z * w2[m] + a4.w * w3[m];
        }
    }
    {
        const float* Wk = Wb + (size_t)200 * HH1;
        float wl0 = Wk[0], wl1 = Wk[32];
        #pragma unroll
        for (int r = 0; r < 8; ++r) {
            float av = S[rg * 8 + r][200];
            acc[r][0] += av * wl0;
            acc[r][1] += av * wl1;
        }
    }
    #pragma unroll
    for (int r = 0; r < 8; ++r) {
        int b = bt * 64 + rg * 8 + r;
        float* Ur = U + (size_t)b * NU + i * HH1 + half * 64 + c;
        Ur[0] = acc[r][0];
        Ur[32] = acc[r][1];
    }
}

__global__ void k_fc1b(const float* __restrict__ U, const float* __restrict__ hg,
                       float* __restrict__ o1) {
    int idx = blockIdx.x * 256 + threadIdx.x;   // 65536
    int b = idx >> 7, j = idx & 127;
    const float* Ub = U + (size_t)b * NU + j;
    const float* hgb = hg + b * C2;
    float acc = Ub[20 * HH1];
    #pragma unroll
    for (int i = 0; i < 20; ++i) acc += hgb[i] * Ub[i * HH1];
    o1[idx] = acc;
}

// ---------------- batch-norm stats ----------------
__global__ void k_bnstats(const float* __restrict__ x, float* __restrict__ stats,
                          int ncols, int nrows) {
    __shared__ float sh[1024], sh2[1024];
    const int tid = threadIdx.x;
    const int j = tid % ncols;
    const int r = tid / ncols;
    const int R = 1024 / ncols;
    float s = 0.f, s2 = 0.f;
    for (int b = r; b < nrows; b += R) {
        float v = x[b * ncols + j];
        s += v; s2 += v * v;
    }
    sh[tid] = s; sh2[tid] = s2;
    __syncthreads();
    if (r == 0) {
        for (int q = 1; q < R; ++q) { s += sh[q * ncols + j]; s2 += sh2[q * ncols + j]; }
        float mu = s / nrows;
        float var = s2 / nrows - mu * mu;
        stats[j] = mu;
        stats[ncols + j] = rsqrtf(var + 1e-5f);
    }
}

// ---------------- fc2 (bn1 + relu fused) ----------------
__global__ void k_fc2(const float* __restrict__ o1, const float* __restrict__ st1,
                      const float* __restrict__ g, const float* __restrict__ beta,
                      const float* __restrict__ W, float* __restrict__ o2) {
    __shared__ float r[HH1];
    __shared__ float part[4][HH2];
    int b = blockIdx.x;
    int tid = threadIdx.x;   // 128
    float v = o1[b * HH1 + tid];
    float nv = (v - st1[tid]) * st1[HH1 + tid] * g[tid] + beta[tid];
    r[tid] = fmaxf(nv, 0.f);
    __syncthreads();
    int m = tid & 31, p = tid >> 5;
    float acc = 0.f;
    #pragma unroll 4
    for (int j = p * 32; j < p * 32 + 32; ++j) acc += r[j] * W[j * HH2 + m];
    part[p][m] = acc;
    __syncthreads();
    if (tid < HH2) o2[b * HH2 + tid] = part[0][tid] + part[1][tid] + part[2][tid] + part[3][tid];
}

// ---------------- bn2 + relu + fc3 ----------------
__global__ void k_final(const float* __restrict__ o2, const float* __restrict__ st2,
                        const float* __restrict__ g, const float* __restrict__ beta,
                        const float* __restrict__ W3, const float* __restrict__ b3,
                        float* __restrict__ out) {
    int b = threadIdx.x;    // 512
    if (b < NB) {
        float acc = b3[0];
        #pragma unroll 4
        for (int m = 0; m < HH2; ++m) {
            float v = o2[b * HH2 + m];
            float nv = (v - st2[m]) * st2[HH2 + m] * g[m] + beta[m];
            acc += fmaxf(nv, 0.f) * W3[m];
        }
        out[b] = acc;
    }
}

extern "C" void kernel_launch(void* const* d_in, const int* in_sizes, int n_in,
                              void* d_out, int out_size, void* d_ws, size_t ws_size,
                              hipStream_t stream) {
    const float* feat   = (const float*)d_in[0];
    const float* desc2d = (const float*)d_in[1];
    const float* gc1W = (const float*)d_in[3];
    const float* gc1b = (const float*)d_in[4];
    const float* gc2W = (const float*)d_in[5];
    const float* gc2b = (const float*)d_in[6];
    const float* pgW  = (const float*)d_in[7];
    const float* pgb  = (const float*)d_in[8];
    const float* p2W  = (const float*)d_in[9];
    const float* p2b  = (const float*)d_in[10];
    const float* W2   = (const float*)d_in[11];
    const float* fc1W = (const float*)d_in[12];
    const float* fc2W = (const float*)d_in[14];
    const float* fc3W = (const float*)d_in[16];
    const float* fc3b = (const float*)d_in[17];
    const float* bn1g = (const float*)d_in[18];
    const float* bn1b = (const float*)d_in[19];
    const float* bn2g = (const float*)d_in[20];
    const float* bn2b = (const float*)d_in[21];
    const int* src = (const int*)d_in[22];
    const int* dst = (const int*)d_in[23];
    const int* gid = (const int*)d_in[24];
    float* out = (float*)d_out;

    char* ws = (char*)d_ws;
    size_t off = 0;
    auto alloc = [&](size_t nb) {
        void* p = ws + off;
        off = (off + nb + 255) & ~(size_t)255;
        return p;
    };
    unsigned* t1b = (unsigned*)alloc((size_t)NN * 50 * 4);   // 10 MB packed bf16
    unsigned* h1b = (unsigned*)alloc((size_t)NN * 50 * 4);   // 10 MB packed bf16
    float* t2    = (float*)alloc((size_t)NN * C2 * 4);       // 4 MB
    int* cnt_in  = (int*)alloc((size_t)NN * 4);
    int* row_ptr = (int*)alloc((size_t)(NN + 1) * 4);
    int* cursor  = (int*)alloc((size_t)NN * 4);
    int* elist   = (int*)alloc((size_t)NE * 4);
    int* bsum    = (int*)alloc((size_t)256 * 4);
    int* gcnt    = (int*)alloc((size_t)NB * 4);
    float* hgs   = (float*)alloc((size_t)NB * C2 * 4);
    float* hg    = (float*)alloc((size_t)NB * C2 * 4);
    float* o1    = (float*)alloc((size_t)NB * HH1 * 4);
    float* st1   = (float*)alloc(2 * HH1 * 4);
    float* o2    = (float*)alloc((size_t)NB * HH2 * 4);
    float* st2   = (float*)alloc(2 * HH2 * 4);
    // fc1 scratch aliases t1b (dead after k_agg1)
    float* U     = (float*)t1b;                              // 5.5 MB < 10 MB
    float* d1ext = U + (size_t)NB * NU;

    hipMemsetAsync(cnt_in, 0, (size_t)NN * 4, stream);
    hipMemsetAsync(gcnt, 0, (size_t)NB * 4, stream);
    hipMemsetAsync(hgs, 0, (size_t)NB * C2 * 4, stream);

    k_countg<<<(NE + 255) / 256, 256, 0, stream>>>(dst, cnt_in, gid, gcnt);
    k_scan1<<<SCB, 256, 0, stream>>>(cnt_in, row_ptr, bsum);
    k_scan2<<<1, 256, 0, stream>>>(bsum, row_ptr);
    k_scan3<<<SCB, 256, 0, stream>>>(row_ptr, bsum, cursor);
    k_fill<<<(NE + 255) / 256, 256, 0, stream>>>(src, dst, cursor, elist);

    k_gemm1<<<512, 256, 0, stream>>>(feat, gc1W, t1b);
    k_agg1<<<(NN + 3) / 4, 256, 0, stream>>>(t1b, row_ptr, elist, gc1b, h1b);
    k_gemm2<<<(NN + 15) / 16, 320, 0, stream>>>(h1b, gc2W, t2);
    k_agg2p<<<(NN + 11) / 12, 256, 0, stream>>>(t2, row_ptr, elist, gc2b, gid, hgs);

    k_headp<<<NB, 64, 0, stream>>>(hgs, gcnt, desc2d, pgW, pgb, p2W, p2b, W2, hg, d1ext);

    dim3 g1(16, 21);
    k_fc1<<<g1, 256, 0, stream>>>(d1ext, fc1W, U);
    k_fc1b<<<NB * HH1 / 256, 256, 0, stream>>>(U, hg, o1);

    k_bnstats<<<1, 1024, 0, stream>>>(o1, st1, HH1, NB);
    k_fc2<<<NB, 128, 0, stream>>>(o1, st1, bn1g, bn1b, fc2W, o2);
    k_bnstats<<<1, 1024, 0, stream>>>(o2, st2, HH2, NB);
    k_final<<<1, 512, 0, stream>>>(o2, st2, bn2g, bn2b, fc3W, fc3b, out);
}